// Round 5
// baseline (389.544 us; speedup 1.0000x reference)
//
#include <hip/hip_runtime.h>
#include <hip/hip_bf16.h>
#include <math.h>

#define N_NODES 50000
#define F_IN 256
#define H1 128
#define C_OUT 40
#define L1W 384   // 3*H1
#define L2W 120   // 3*C_OUT
#define L2WP 128  // padded
#define NBUK 196  // ceil(50000/256) dst buckets of 256 nodes
#define NBLK1 256 // phase-1 blocks

typedef __attribute__((ext_vector_type(8))) short short8;
typedef __attribute__((ext_vector_type(4))) float f32x4;
typedef __attribute__((ext_vector_type(2))) float f32x2;

typedef __attribute__((address_space(1))) const unsigned int gu32;
typedef __attribute__((address_space(3))) unsigned int lu32;

__device__ __forceinline__ void g2l16(const void* g, void* l) {
    __builtin_amdgcn_global_load_lds((gu32*)g, (lu32*)l, 16, 0, 0);
}

__device__ inline unsigned short f2bf(float f) {
    union { float f; unsigned int u; } x;
    x.f = f;
    unsigned int u = x.u;
    return (unsigned short)((u + 0x7FFF + ((u >> 16) & 1)) >> 16);
}
__device__ inline float bf2f(unsigned short u) {
    union { unsigned int u; float f; } x;
    x.u = (unsigned int)u << 16;
    return x.f;
}
__device__ inline unsigned int pack_fp8x4(float a, float b, float c, float d) {
    int v = 0;
    v = __builtin_amdgcn_cvt_pk_fp8_f32(a, b, v, false);  // bytes 0,1
    v = __builtin_amdgcn_cvt_pk_fp8_f32(c, d, v, true);   // bytes 2,3
    return (unsigned int)v;
}
__device__ inline unsigned short pack_fp8x2(float a, float b) {
    return (unsigned short)(__builtin_amdgcn_cvt_pk_fp8_f32(a, b, 0, false) & 0xFFFF);
}
__device__ inline unsigned char pack_fp8x1(float a) {
    return (unsigned char)(__builtin_amdgcn_cvt_pk_fp8_f32(a, a, 0, false) & 0xFF);
}
// decode 4B edge record {w:bf16:16 | src:16}
#define EDGE_S(r) ((int)((r) & 0xFFFFu))
#define EDGE_W(r) bf2f((unsigned short)((r) >> 16))

// ---------------- edge-index dtype detection --------------------------------

__global__ void detect_k(const int* __restrict__ ei, int* __restrict__ flag) {
    __shared__ int any;
    if (threadIdx.x == 0) any = 0;
    __syncthreads();
    int v = 0;
    for (int r = 0; r < 4; r++) {
        int e = threadIdx.x + r * 256;
        v |= ei[e * 2 + 1];
    }
    if (v != 0) atomicOr(&any, 1);
    __syncthreads();
    if (threadIdx.x == 0) *flag = any;  // 1 => int32 layout, 0 => int64
}

// ---------------- per-node degree histogram ---------------------------------

__global__ void hist_k(const int* __restrict__ ei, const int* __restrict__ flag,
                       int* __restrict__ cnt, int E) {
    int base = (blockIdx.x * 256 + threadIdx.x) * 4;
    if (base >= E) return;
    if (base + 4 <= E) {
        int d0, d1, d2, d3;
        if (*flag) {
            int4 dv = *(const int4*)(ei + E + base);
            d0 = dv.x; d1 = dv.y; d2 = dv.z; d3 = dv.w;
        } else {
            const long long* e64 = (const long long*)ei;
            longlong2 a = *(const longlong2*)(e64 + E + base);
            longlong2 b = *(const longlong2*)(e64 + E + base + 2);
            d0 = (int)a.x; d1 = (int)a.y; d2 = (int)b.x; d3 = (int)b.y;
        }
        atomicAdd(&cnt[d0], 1);
        atomicAdd(&cnt[d1], 1);
        atomicAdd(&cnt[d2], 1);
        atomicAdd(&cnt[d3], 1);
    } else {
        for (int e = base; e < E; e++) {
            int d = (*flag) ? ei[E + e] : (int)((const long long*)ei)[E + e];
            atomicAdd(&cnt[d], 1);
        }
    }
}

// ---------------- generic 3-level exclusive scan ----------------------------

__global__ __launch_bounds__(256) void scan1_k(const int* __restrict__ cnt,
                                               int* __restrict__ bsum, int n) {
    int t = threadIdx.x;
    int i = blockIdx.x * 256 + t;
    int v = (i < n) ? cnt[i] : 0;
    for (int off = 32; off; off >>= 1) v += __shfl_down(v, off, 64);
    __shared__ int ws[4];
    if ((t & 63) == 0) ws[t >> 6] = v;
    __syncthreads();
    if (t == 0) bsum[blockIdx.x] = ws[0] + ws[1] + ws[2] + ws[3];
}

__global__ __launch_bounds__(256) void scan2_k(int* __restrict__ bsum,
                                               int* __restrict__ btot, int nb) {
    __shared__ int s[256];
    int t = threadIdx.x;
    int v = (t < nb) ? bsum[t] : 0;
    s[t] = v;
    __syncthreads();
    for (int off = 1; off < 256; off <<= 1) {
        int u = (t >= off) ? s[t - off] : 0;
        __syncthreads();
        s[t] += u;
        __syncthreads();
    }
    if (t < nb) bsum[t] = s[t] - v;  // exclusive
    if (t == nb - 1) *btot = s[t];
}

// scan3 + optional dinv fusion (dinv != nullptr only for the node scan)
__global__ __launch_bounds__(256) void scan3_k(const int* __restrict__ cnt,
                                               const int* __restrict__ bsum,
                                               int* __restrict__ rowptr,
                                               float* __restrict__ dinv, int n) {
    __shared__ int s[256];
    int t = threadIdx.x;
    int i = blockIdx.x * 256 + t;
    int v = (i < n) ? cnt[i] : 0;
    s[t] = v;
    __syncthreads();
    for (int off = 1; off < 256; off <<= 1) {
        int u = (t >= off) ? s[t - off] : 0;
        __syncthreads();
        s[t] += u;
        __syncthreads();
    }
    if (i < n) {
        rowptr[i] = s[t] - v + bsum[blockIdx.x];
        if (dinv) dinv[i] = rsqrtf((float)v + 1.0f);
    }
}

// ---------------- two-phase binned scatter ----------------------------------

__global__ __launch_bounds__(256) void hist2_k(const int* __restrict__ ei,
                                               const int* __restrict__ flag,
                                               int* __restrict__ cnt2, int E) {
    __shared__ int lcnt[NBUK];
    int t = threadIdx.x, blk = blockIdx.x;
    for (int j = t; j < NBUK; j += 256) lcnt[j] = 0;
    __syncthreads();
    int chunk = (E + NBLK1 - 1) / NBLK1;
    int beg = blk * chunk, end = min(beg + chunk, E);
    bool i32 = (*flag) != 0;
    const long long* e64 = (const long long*)ei;
    for (int e = beg + t; e < end; e += 256) {
        int d = i32 ? ei[E + e] : (int)e64[E + e];
        atomicAdd(&lcnt[d >> 8], 1);
    }
    __syncthreads();
    for (int j = t; j < NBUK; j += 256) cnt2[j * NBLK1 + blk] = lcnt[j];  // bucket-major
}

__global__ __launch_bounds__(256) void stage_k(const int* __restrict__ ei,
                                               const int* __restrict__ flag,
                                               const int* __restrict__ off2,
                                               unsigned int* __restrict__ stage, int E) {
    __shared__ int lcur[NBUK];
    int t = threadIdx.x, blk = blockIdx.x;
    for (int j = t; j < NBUK; j += 256) lcur[j] = off2[j * NBLK1 + blk];
    __syncthreads();
    int chunk = (E + NBLK1 - 1) / NBLK1;
    int beg = blk * chunk, end = min(beg + chunk, E);
    bool i32 = (*flag) != 0;
    const long long* e64 = (const long long*)ei;
    for (int e = beg + t; e < end; e += 256) {
        int s, d;
        if (i32) { s = ei[e]; d = ei[E + e]; }
        else { s = (int)e64[e]; d = (int)e64[E + e]; }
        int b = d >> 8;
        int pos = atomicAdd(&lcur[b], 1);
        stage[pos] = ((unsigned int)(d & 255) << 16) | (unsigned int)s;
    }
}

__global__ __launch_bounds__(256) void scatter2_k(const unsigned int* __restrict__ stage,
                                                  const int* __restrict__ off2,
                                                  const int* __restrict__ rowptr,
                                                  const float* __restrict__ dinv,
                                                  unsigned int* __restrict__ csr,
                                                  int E, int n) {
    __shared__ int lfill[256];
    int b = blockIdx.x, t = threadIdx.x;
    int node0 = b << 8;
    int node = node0 + t;
    lfill[t] = (node < n) ? rowptr[node] : 0;
    __syncthreads();
    int segBeg = off2[b * NBLK1];
    int segEnd = (b == NBUK - 1) ? E : off2[(b + 1) * NBLK1];
    for (int e = segBeg + t; e < segEnd; e += 256) {
        unsigned int rec = stage[e];
        int dl = rec >> 16;
        int s = rec & 0xFFFF;
        int d = node0 + dl;
        float w = dinv[s] * dinv[d];
        int pos = atomicAdd(&lfill[dl], 1);
        csr[pos] = ((unsigned int)f2bf(w) << 16) | (unsigned int)s;
    }
}

// ---------------- weight packing (bf16, B-fragment layout), merged ----------
// NEW tile-internal layout: within each 512-short tile: off = kq*128 + m*8 + kk
// (col = s*16+m, k = kt*32 + kq*8 + kk) -> ds_read of a frag is linear 16B/lane.

#define N1PACK ((F_IN / 32) * L1W * 32)
#define N2PACK ((L1W / 32) * L2WP * 32)

__global__ void pack_k(const float* __restrict__ w10, const float* __restrict__ w11,
                       const float* __restrict__ w12, const float* __restrict__ w20,
                       const float* __restrict__ w21, const float* __restrict__ w22,
                       unsigned short* __restrict__ Bp1, unsigned short* __restrict__ Bp2) {
    int idx = blockIdx.x * 256 + threadIdx.x;
    if (idx < N1PACK) {
        int kt = idx / (L1W * 32);
        int t = idx % (L1W * 32);
        int s = t >> 9;
        int u = t & 511;
        int kq = u >> 7, m = (u >> 3) & 15, kk = u & 7;
        int col = s * 16 + m;
        int k = kt * 32 + kq * 8 + kk;
        int p = col >> 7, c = col & 127;
        const float* w = (p == 0) ? w10 : (p == 1) ? w11 : w12;
        Bp1[idx] = f2bf(w[k * H1 + c]);
    } else if (idx < N1PACK + N2PACK) {
        int j = idx - N1PACK;
        int kt = j / (L2WP * 32);
        int t = j % (L2WP * 32);
        int s = t >> 9;
        int u = t & 511;
        int kq = u >> 7, m = (u >> 3) & 15, kk = u & 7;
        int col = s * 16 + m;
        int k = kt * 32 + kq * 8 + kk;
        unsigned short v = 0;
        if (col < L2W) {
            int p = col / 40, c = col % 40;
            const float* w = (p == 0) ? w20 : (p == 1) ? w21 : w22;
            v = f2bf(w[k * C_OUT + c]);
        }
        Bp2[j] = v;
    }
}

// ---------------- layer-1 GEMM: wave-autonomous, LDS-direct B, counted waits
// Block = 64 rows, 4 waves; wave w owns N-tiles gs = 6w..6w+5 (96 cols) and all
// 64 rows (4 M-frags). B staged via global_load_lds into a wave-PRIVATE 2-slot
// LDS slice (no barriers, no dest VGPRs -> regalloc can't serialize loads).
// 2-deep prefetch, steady-state s_waitcnt vmcnt(6) (never 0 until the tail).

__global__ __launch_bounds__(256, 2) void mgemm1_k(const float* __restrict__ A,
                                                   const unsigned short* __restrict__ Bp,
                                                   const float* __restrict__ b1,
                                                   unsigned short* __restrict__ Hb,
                                                   unsigned char* __restrict__ Y8, int N) {
    __shared__ unsigned short Bls[4][2][3072];  // per-wave 2 slots x 6 tiles x 1KB
    int tid = threadIdx.x;
    int w = tid >> 6, lane = tid & 63;
    int m = lane & 15, kq = lane >> 4;
    int row0 = blockIdx.x * 64;
    const char* srcb = (const char*)Bp + (size_t)(w * 6) * 1024 + (size_t)lane * 16;

    const float* Ap0;
    const float* Ap1;
    const float* Ap2;
    const float* Ap3;
    {
        int a0 = row0 + 0 * 16 + m; if (a0 >= N) a0 = N - 1;
        int a1 = row0 + 1 * 16 + m; if (a1 >= N) a1 = N - 1;
        int a2 = row0 + 2 * 16 + m; if (a2 >= N) a2 = N - 1;
        int a3 = row0 + 3 * 16 + m; if (a3 >= N) a3 = N - 1;
        Ap0 = A + (size_t)a0 * F_IN + kq * 8;
        Ap1 = A + (size_t)a1 * F_IN + kq * 8;
        Ap2 = A + (size_t)a2 * F_IN + kq * 8;
        Ap3 = A + (size_t)a3 * F_IN + kq * 8;
    }

    f32x4 acc[4][6];
#pragma unroll
    for (int f = 0; f < 4; f++)
#pragma unroll
        for (int j = 0; j < 6; j++) acc[f][j] = (f32x4){0.f, 0.f, 0.f, 0.f};

    float4 afA[4][2], afB[4][2];
    // prologue: A(0) regs; G2L(0)->slot0; G2L(1)->slot1
    afA[0][0] = *(const float4*)(Ap0); afA[0][1] = *(const float4*)(Ap0 + 4);
    afA[1][0] = *(const float4*)(Ap1); afA[1][1] = *(const float4*)(Ap1 + 4);
    afA[2][0] = *(const float4*)(Ap2); afA[2][1] = *(const float4*)(Ap2 + 4);
    afA[3][0] = *(const float4*)(Ap3); afA[3][1] = *(const float4*)(Ap3 + 4);
#pragma unroll
    for (int j = 0; j < 6; j++) g2l16(srcb + j * 1024, &Bls[w][0][j * 512]);
#pragma unroll
    for (int j = 0; j < 6; j++) g2l16(srcb + 24576 + j * 1024, &Bls[w][1][j * 512]);

#pragma unroll
    for (int kt = 0; kt < 8; kt++) {
        // wait: B(kt) in LDS (A(kt) regs are compiler-protected)
        if (kt < 7) { asm volatile("s_waitcnt vmcnt(6)" ::: "memory"); }
        else        { asm volatile("s_waitcnt vmcnt(0)" ::: "memory"); }
        __builtin_amdgcn_sched_barrier(0);
        short8 bf[6];
#pragma unroll
        for (int j = 0; j < 6; j++)
            bf[j] = *(const short8*)(&Bls[w][kt & 1][j * 512 + kq * 128 + m * 8]);
        asm volatile("s_waitcnt lgkmcnt(0)" ::: "memory");  // reads retired -> slot reusable
        __builtin_amdgcn_sched_barrier(0);
        // issue A(kt+1) into the other buffer
        if (kt < 7) {
            if ((kt & 1) == 0) {
                afB[0][0] = *(const float4*)(Ap0 + (kt + 1) * 32); afB[0][1] = *(const float4*)(Ap0 + (kt + 1) * 32 + 4);
                afB[1][0] = *(const float4*)(Ap1 + (kt + 1) * 32); afB[1][1] = *(const float4*)(Ap1 + (kt + 1) * 32 + 4);
                afB[2][0] = *(const float4*)(Ap2 + (kt + 1) * 32); afB[2][1] = *(const float4*)(Ap2 + (kt + 1) * 32 + 4);
                afB[3][0] = *(const float4*)(Ap3 + (kt + 1) * 32); afB[3][1] = *(const float4*)(Ap3 + (kt + 1) * 32 + 4);
            } else {
                afA[0][0] = *(const float4*)(Ap0 + (kt + 1) * 32); afA[0][1] = *(const float4*)(Ap0 + (kt + 1) * 32 + 4);
                afA[1][0] = *(const float4*)(Ap1 + (kt + 1) * 32); afA[1][1] = *(const float4*)(Ap1 + (kt + 1) * 32 + 4);
                afA[2][0] = *(const float4*)(Ap2 + (kt + 1) * 32); afA[2][1] = *(const float4*)(Ap2 + (kt + 1) * 32 + 4);
                afA[3][0] = *(const float4*)(Ap3 + (kt + 1) * 32); afA[3][1] = *(const float4*)(Ap3 + (kt + 1) * 32 + 4);
            }
        }
        // issue G2L(kt+2) into the slot we just finished reading
        if (kt < 6) {
#pragma unroll
            for (int j = 0; j < 6; j++)
                g2l16(srcb + (size_t)(kt + 2) * 24576 + j * 1024, &Bls[w][kt & 1][j * 512]);
        }
        // convert A(kt) and MFMA
        short8 av[4];
#pragma unroll
        for (int f = 0; f < 4; f++) {
            float4 u = (kt & 1) ? afB[f][0] : afA[f][0];
            float4 v = (kt & 1) ? afB[f][1] : afA[f][1];
            short8 a;
            a[0] = (short)f2bf(u.x); a[1] = (short)f2bf(u.y);
            a[2] = (short)f2bf(u.z); a[3] = (short)f2bf(u.w);
            a[4] = (short)f2bf(v.x); a[5] = (short)f2bf(v.y);
            a[6] = (short)f2bf(v.z); a[7] = (short)f2bf(v.w);
            av[f] = a;
        }
#pragma unroll
        for (int f = 0; f < 4; f++)
#pragma unroll
            for (int j = 0; j < 6; j++)
                acc[f][j] = __builtin_amdgcn_mfma_f32_16x16x32_bf16(av[f], bf[j], acc[f][j], 0, 0, 0);
    }

    int crow0 = row0 + kq * 4;
    if (w == 0) {  // gs 0..5 -> Hb cols 0..95
#pragma unroll
        for (int j = 0; j < 6; j++) {
            int col = j * 16 + m;
            float bias = b1[col];
#pragma unroll
            for (int f = 0; f < 4; f++)
#pragma unroll
                for (int r2 = 0; r2 < 4; r2++) {
                    int row = crow0 + f * 16 + r2;
                    if (row < N) Hb[(size_t)row * L1W + col] = f2bf(fmaxf(acc[f][j][r2] + bias, 0.f));
                }
        }
    } else if (w == 1) {  // gs 6,7 -> Hb cols 96..127; gs 8..11 -> Y8 bytes 0..3
#pragma unroll
        for (int j = 0; j < 2; j++) {
            int col = (6 + j) * 16 + m;
            float bias = b1[col];
#pragma unroll
            for (int f = 0; f < 4; f++)
#pragma unroll
                for (int r2 = 0; r2 < 4; r2++) {
                    int row = crow0 + f * 16 + r2;
                    if (row < N) Hb[(size_t)row * L1W + col] = f2bf(fmaxf(acc[f][j][r2] + bias, 0.f));
                }
        }
#pragma unroll
        for (int f = 0; f < 4; f++)
#pragma unroll
            for (int r2 = 0; r2 < 4; r2++) {
                int row = crow0 + f * 16 + r2;
                if (row < N) {
                    unsigned int u = pack_fp8x4(acc[f][2][r2], acc[f][3][r2], acc[f][4][r2], acc[f][5][r2]);
                    *(unsigned int*)(Y8 + (size_t)row * 256 + m * 16) = u;
                }
            }
    } else if (w == 2) {  // gs 12..17 -> Y8 bytes 4..9
#pragma unroll
        for (int f = 0; f < 4; f++)
#pragma unroll
            for (int r2 = 0; r2 < 4; r2++) {
                int row = crow0 + f * 16 + r2;
                if (row < N) {
                    unsigned int u = pack_fp8x4(acc[f][0][r2], acc[f][1][r2], acc[f][2][r2], acc[f][3][r2]);
                    unsigned short v = pack_fp8x2(acc[f][4][r2], acc[f][5][r2]);
                    *(unsigned int*)(Y8 + (size_t)row * 256 + m * 16 + 4) = u;
                    *(unsigned short*)(Y8 + (size_t)row * 256 + m * 16 + 8) = v;
                }
            }
    } else {  // gs 18..23 -> Y8 bytes 10..15
#pragma unroll
        for (int f = 0; f < 4; f++)
#pragma unroll
            for (int r2 = 0; r2 < 4; r2++) {
                int row = crow0 + f * 16 + r2;
                if (row < N) {
                    unsigned short v = pack_fp8x2(acc[f][0][r2], acc[f][1][r2]);
                    unsigned int u = pack_fp8x4(acc[f][2][r2], acc[f][3][r2], acc[f][4][r2], acc[f][5][r2]);
                    *(unsigned short*)(Y8 + (size_t)row * 256 + m * 16 + 10) = v;
                    *(unsigned int*)(Y8 + (size_t)row * 256 + m * 16 + 12) = u;
                }
            }
    }
}

// ---------------- layer-2 GEMM: same wave-autonomous structure --------------
// Block = 64 rows, wave w owns tiles gs = 2w, 2w+1 (cols 32w..32w+31). K=384.

__global__ __launch_bounds__(256, 3) void mgemm2_k(const unsigned short* __restrict__ A,
                                                   const unsigned short* __restrict__ Bp,
                                                   unsigned short* __restrict__ Ub,
                                                   unsigned char* __restrict__ U8, int N) {
    __shared__ unsigned short Bls[4][2][1024];  // per-wave 2 slots x 2 tiles x 1KB
    int tid = threadIdx.x;
    int w = tid >> 6, lane = tid & 63;
    int m = lane & 15, kq = lane >> 4;
    int row0 = blockIdx.x * 64;
    const char* srcb = (const char*)Bp + (size_t)(w * 2) * 1024 + (size_t)lane * 16;

    const unsigned short* Ap0;
    const unsigned short* Ap1;
    const unsigned short* Ap2;
    const unsigned short* Ap3;
    {
        int a0 = row0 + 0 * 16 + m; if (a0 >= N) a0 = N - 1;
        int a1 = row0 + 1 * 16 + m; if (a1 >= N) a1 = N - 1;
        int a2 = row0 + 2 * 16 + m; if (a2 >= N) a2 = N - 1;
        int a3 = row0 + 3 * 16 + m; if (a3 >= N) a3 = N - 1;
        Ap0 = A + (size_t)a0 * L1W + kq * 8;
        Ap1 = A + (size_t)a1 * L1W + kq * 8;
        Ap2 = A + (size_t)a2 * L1W + kq * 8;
        Ap3 = A + (size_t)a3 * L1W + kq * 8;
    }

    f32x4 acc[4][2];
#pragma unroll
    for (int f = 0; f < 4; f++)
#pragma unroll
        for (int j = 0; j < 2; j++) acc[f][j] = (f32x4){0.f, 0.f, 0.f, 0.f};

    short8 afA[4], afB[4];
    afA[0] = *(const short8*)(Ap0);
    afA[1] = *(const short8*)(Ap1);
    afA[2] = *(const short8*)(Ap2);
    afA[3] = *(const short8*)(Ap3);
#pragma unroll
    for (int j = 0; j < 2; j++) g2l16(srcb + j * 1024, &Bls[w][0][j * 512]);
#pragma unroll
    for (int j = 0; j < 2; j++) g2l16(srcb + 8192 + j * 1024, &Bls[w][1][j * 512]);

#pragma unroll
    for (int kt = 0; kt < 12; kt++) {
        if (kt < 11) { asm volatile("s_waitcnt vmcnt(2)" ::: "memory"); }
        else         { asm volatile("s_waitcnt vmcnt(0)" ::: "memory"); }
        __builtin_amdgcn_sched_barrier(0);
        short8 bf[2];
#pragma unroll
        for (int j = 0; j < 2; j++)
            bf[j] = *(const short8*)(&Bls[w][kt & 1][j * 512 + kq * 128 + m * 8]);
        asm volatile("s_waitcnt lgkmcnt(0)" ::: "memory");
        __builtin_amdgcn_sched_barrier(0);
        if (kt < 11) {
            if ((kt & 1) == 0) {
                afB[0] = *(const short8*)(Ap0 + (kt + 1) * 32);
                afB[1] = *(const short8*)(Ap1 + (kt + 1) * 32);
                afB[2] = *(const short8*)(Ap2 + (kt + 1) * 32);
                afB[3] = *(const short8*)(Ap3 + (kt + 1) * 32);
            } else {
                afA[0] = *(const short8*)(Ap0 + (kt + 1) * 32);
                afA[1] = *(const short8*)(Ap1 + (kt + 1) * 32);
                afA[2] = *(const short8*)(Ap2 + (kt + 1) * 32);
                afA[3] = *(const short8*)(Ap3 + (kt + 1) * 32);
            }
        }
        if (kt < 10) {
#pragma unroll
            for (int j = 0; j < 2; j++)
                g2l16(srcb + (size_t)(kt + 2) * 8192 + j * 1024, &Bls[w][kt & 1][j * 512]);
        }
#pragma unroll
        for (int f = 0; f < 4; f++) {
            short8 a = (kt & 1) ? afB[f] : afA[f];
#pragma unroll
            for (int j = 0; j < 2; j++)
                acc[f][j] = __builtin_amdgcn_mfma_f32_16x16x32_bf16(a, bf[j], acc[f][j], 0, 0, 0);
        }
    }

    int crow0 = row0 + kq * 4;
    // U8: bytes m*8 + 2w + {0,1}
#pragma unroll
    for (int f = 0; f < 4; f++)
#pragma unroll
        for (int r2 = 0; r2 < 4; r2++) {
            int row = crow0 + f * 16 + r2;
            if (row < N) {
                unsigned short v = pack_fp8x2(acc[f][0][r2], acc[f][1][r2]);
                *(unsigned short*)(U8 + (size_t)row * 128 + m * 8 + 2 * w) = v;
            }
        }
    // Ub: cols < 48 (gs 0,1 from wave 0; gs 2 from wave 1)
    if (w == 0) {
#pragma unroll
        for (int j = 0; j < 2; j++) {
            int col = j * 16 + m;
#pragma unroll
            for (int f = 0; f < 4; f++)
#pragma unroll
                for (int r2 = 0; r2 < 4; r2++) {
                    int row = crow0 + f * 16 + r2;
                    if (row < N) Ub[(size_t)row * L2WP + col] = f2bf(acc[f][j][r2]);
                }
        }
    } else if (w == 1) {
        int col = 32 + m;
#pragma unroll
        for (int f = 0; f < 4; f++)
#pragma unroll
            for (int r2 = 0; r2 < 4; r2++) {
                int row = crow0 + f * 16 + r2;
                if (row < N) Ub[(size_t)row * L2WP + col] = f2bf(acc[f][0][r2]);
            }
    }
}

// ---------------- fused width-256 fp8 prop over Y8 --------------------------
// pipelined: ping-pong csr prefetch (rrA/rrB) + masked final batch (no serial tail)

__global__ __launch_bounds__(256) void prop256f_k(const unsigned char* __restrict__ Y8,
                                                  unsigned short* __restrict__ Hb,
                                                  unsigned char* __restrict__ T8,
                                                  const int* __restrict__ rowptr,
                                                  const unsigned int* __restrict__ csr,
                                                  const float* __restrict__ dinv,
                                                  const float* __restrict__ b1, int n) {
    int wave = threadIdx.x >> 6, lane = threadIdx.x & 63;
    int i = blockIdx.x * 4 + wave;
    if (i >= n) return;
    int beg = rowptr[i], end = rowptr[i + 1];
    float di = dinv[i];
    const unsigned int* sbase = (const unsigned int*)Y8 + lane;  // row stride 64 uints
    unsigned int sv = sbase[(size_t)i * 64];
    float w = di * di;
    f32x2 slo = __builtin_amdgcn_cvt_pk_f32_fp8(sv, false);
    f32x2 shi = __builtin_amdgcn_cvt_pk_f32_fp8(sv, true);
    float a0 = w * slo.x, a1 = w * slo.y, a2 = w * shi.x, a3 = w * shi.y;

#define CONS256(rr, vv)                                                       \
    _Pragma("unroll") for (int e = 0; e < 8; e++) {                           \
        float we = EDGE_W(rr[e]);                                             \
        f32x2 lo = __builtin_amdgcn_cvt_pk_f32_fp8(vv[e], false);             \
        f32x2 hi = __builtin_amdgcn_cvt_pk_f32_fp8(vv[e], true);              \
        a0 = fmaf(we, lo.x, a0);                                              \
        a1 = fmaf(we, lo.y, a1);                                              \
        a2 = fmaf(we, hi.x, a2);                                              \
        a3 = fmaf(we, hi.y, a3);                                              \
    }

    int nfull = (end - beg) >> 3;
    unsigned int rrA[8], rrB[8];
    if (nfull > 0) {
#pragma unroll
        for (int e = 0; e < 8; e++) rrA[e] = csr[beg + e];
        int it = 0;
        while (it + 2 <= nfull) {
            {
                unsigned int vv[8];
#pragma unroll
                for (int e = 0; e < 8; e++) vv[e] = sbase[(size_t)EDGE_S(rrA[e]) * 64];
#pragma unroll
                for (int e = 0; e < 8; e++) rrB[e] = csr[beg + ((it + 1) << 3) + e];
                CONS256(rrA, vv)
            }
            {
                unsigned int vv[8];
#pragma unroll
                for (int e = 0; e < 8; e++) vv[e] = sbase[(size_t)EDGE_S(rrB[e]) * 64];
                if (it + 2 < nfull) {
#pragma unroll
                    for (int e = 0; e < 8; e++) rrA[e] = csr[beg + ((it + 2) << 3) + e];
                }
                CONS256(rrB, vv)
            }
            it += 2;
        }
        if (it < nfull) {  // odd last full batch (in rrA)
            unsigned int vv[8];
#pragma unroll
            for (int e = 0; e < 8; e++) vv[e] = sbase[(size_t)EDGE_S(rrA[e]) * 64];
            CONS256(rrA, vv)
        }
    }
    int k = beg + (nfull << 3);
    if (k < end) {  // masked final batch: parallel loads, zeroed weights OOB
        unsigned int rrt[8];
#pragma unroll
        for (int e = 0; e < 8; e++) {
            int idx = k + e;
            rrt[e] = csr[idx < end ? idx : beg];
        }
        unsigned int vv[8];
#pragma unroll
        for (int e = 0; e < 8; e++) vv[e] = sbase[(size_t)EDGE_S(rrt[e]) * 64];
#pragma unroll
        for (int e = 0; e < 8; e++) {
            float we = (k + e < end) ? EDGE_W(rrt[e]) : 0.f;
            f32x2 lo = __builtin_amdgcn_cvt_pk_f32_fp8(vv[e], false);
            f32x2 hi = __builtin_amdgcn_cvt_pk_f32_fp8(vv[e], true);
            a0 = fmaf(we, lo.x, a0);
            a1 = fmaf(we, lo.y, a1);
            a2 = fmaf(we, hi.x, a2);
            a3 = fmaf(we, hi.y, a3);
        }
    }
#undef CONS256
    int m = lane >> 2, jj = lane & 3;
    if (jj < 2) {  // z1: logical cols L_j = (4*jj+j)*16 + m
        float av[4] = {a0, a1, a2, a3};
#pragma unroll
        for (int j = 0; j < 4; j++) {
            int L = (4 * jj + j) * 16 + m;
            Hb[(size_t)i * L1W + 128 + L] = f2bf(fmaxf(av[j] + b1[128 + L], 0.f));
        }
    } else {       // t2 -> T8 phys = m*8 + 4*(jj-2)
        unsigned int o = pack_fp8x4(a0, a1, a2, a3);
        *(unsigned int*)(T8 + (size_t)i * 128 + m * 8 + 4 * (jj - 2)) = o;
    }
}

// ---------------- width-128 fp8 prop: Hb[:,256:384] = relu(P(T8)+b1) --------

__global__ __launch_bounds__(256) void prop128f_k(const unsigned char* __restrict__ T8,
                                                  unsigned short* __restrict__ Hb,
                                                  const int* __restrict__ rowptr,
                                                  const unsigned int* __restrict__ csr,
                                                  const float* __restrict__ dinv,
                                                  const float* __restrict__ b1, int n) {
    int wave = threadIdx.x >> 6, lane = threadIdx.x & 63;
    int i = blockIdx.x * 4 + wave;
    if (i >= n) return;
    int beg = rowptr[i], end = rowptr[i + 1];
    float di = dinv[i];
    const unsigned short* sbase = (const unsigned short*)T8 + lane;  // row stride 64
    unsigned int sv = sbase[(size_t)i * 64];
    float w = di * di;
    f32x2 sd = __builtin_amdgcn_cvt_pk_f32_fp8(sv, false);
    float a0 = w * sd.x, a1 = w * sd.y;

#define CONS128(rr, vv)                                                       \
    _Pragma("unroll") for (int e = 0; e < 8; e++) {                           \
        float we = EDGE_W(rr[e]);                                             \
        f32x2 d = __builtin_amdgcn_cvt_pk_f32_fp8(vv[e], false);              \
        a0 = fmaf(we, d.x, a0);                                               \
        a1 = fmaf(we, d.y, a1);                                               \
    }

    int nfull = (end - beg) >> 3;
    unsigned int rrA[8], rrB[8];
    if (nfull > 0) {
#pragma unroll
        for (int e = 0; e < 8; e++) rrA[e] = csr[beg + e];
        int it = 0;
        while (it + 2 <= nfull) {
            {
                unsigned int vv[8];
#pragma unroll
                for (int e = 0; e < 8; e++) vv[e] = sbase[(size_t)EDGE_S(rrA[e]) * 64];
#pragma unroll
                for (int e = 0; e < 8; e++) rrB[e] = csr[beg + ((it + 1) << 3) + e];
                CONS128(rrA, vv)
            }
            {
                unsigned int vv[8];
#pragma unroll
                for (int e = 0; e < 8; e++) vv[e] = sbase[(size_t)EDGE_S(rrB[e]) * 64];
                if (it + 2 < nfull) {
#pragma unroll
                    for (int e = 0; e < 8; e++) rrA[e] = csr[beg + ((it + 2) << 3) + e];
                }
                CONS128(rrB, vv)
            }
            it += 2;
        }
        if (it < nfull) {
            unsigned int vv[8];
#pragma unroll
            for (int e = 0; e < 8; e++) vv[e] = sbase[(size_t)EDGE_S(rrA[e]) * 64];
            CONS128(rrA, vv)
        }
    }
    int k = beg + (nfull << 3);
    if (k < end) {
        unsigned int rrt[8];
#pragma unroll
        for (int e = 0; e < 8; e++) {
            int idx = k + e;
            rrt[e] = csr[idx < end ? idx : beg];
        }
        unsigned int vv[8];
#pragma unroll
        for (int e = 0; e < 8; e++) vv[e] = sbase[(size_t)EDGE_S(rrt[e]) * 64];
#pragma unroll
        for (int e = 0; e < 8; e++) {
            float we = (k + e < end) ? EDGE_W(rrt[e]) : 0.f;
            f32x2 d = __builtin_amdgcn_cvt_pk_f32_fp8(vv[e], false);
            a0 = fmaf(we, d.x, a0);
            a1 = fmaf(we, d.y, a1);
        }
    }
#undef CONS128
    int m = lane >> 2, u0 = (2 * lane) & 7;
    int L0 = u0 * 16 + m, L1 = (u0 + 1) * 16 + m;
    Hb[(size_t)i * L1W + 256 + L0] = f2bf(fmaxf(a0 + b1[256 + L0], 0.f));
    Hb[(size_t)i * L1W + 256 + L1] = f2bf(fmaxf(a1 + b1[256 + L1], 0.f));
}

// ---------------- layer-2 prop over U8: 2 edge-groups x 32 cols -------------
// batch-of-4 per group + csr ping-pong prefetch + masked final batch

__global__ __launch_bounds__(256) void propU8_k(const unsigned char* __restrict__ U8,
                                                unsigned short* __restrict__ T2a,
                                                unsigned char* __restrict__ T8b,
                                                const int* __restrict__ rowptr,
                                                const unsigned int* __restrict__ csr,
                                                const float* __restrict__ dinv, int n) {
    int wave = threadIdx.x >> 6, lane = threadIdx.x & 63;
    int i = blockIdx.x * 4 + wave;
    if (i >= n) return;
    int beg = rowptr[i], end = rowptr[i + 1];
    float di = dinv[i];
    int g = lane >> 5, c = lane & 31;
    const unsigned int* sbase = (const unsigned int*)U8 + c;  // row stride 32 uints
    float a0 = 0.f, a1 = 0.f, a2 = 0.f, a3 = 0.f;
    if (g == 0) {
        unsigned int sv = sbase[(size_t)i * 32];
        float w = di * di;
        f32x2 lo = __builtin_amdgcn_cvt_pk_f32_fp8(sv, false);
        f32x2 hi = __builtin_amdgcn_cvt_pk_f32_fp8(sv, true);
        a0 = w * lo.x; a1 = w * lo.y; a2 = w * hi.x; a3 = w * hi.y;
    }

#define CONSU8(rr, vv)                                                        \
    _Pragma("unroll") for (int j = 0; j < 4; j++) {                           \
        float we = EDGE_W(rr[j]);                                             \
        f32x2 lo = __builtin_amdgcn_cvt_pk_f32_fp8(vv[j], false);             \
        f32x2 hi = __builtin_amdgcn_cvt_pk_f32_fp8(vv[j], true);              \
        a0 = fmaf(we, lo.x, a0);                                              \
        a1 = fmaf(we, lo.y, a1);                                              \
        a2 = fmaf(we, hi.x, a2);                                              \
        a3 = fmaf(we, hi.y, a3);                                              \
    }

    int k0 = beg + g;                                     // this group's first edge
    int cnt = (k0 < end) ? ((end - k0 + 1) >> 1) : 0;     // edges this group owns
    int nfull = cnt >> 2;
    unsigned int rrA[4], rrB[4];
    if (nfull > 0) {
#pragma unroll
        for (int j = 0; j < 4; j++) rrA[j] = csr[k0 + 2 * j];
        int it = 0;
        while (it + 2 <= nfull) {
            {
                unsigned int vv[4];
#pragma unroll
                for (int j = 0; j < 4; j++) vv[j] = sbase[(size_t)EDGE_S(rrA[j]) * 32];
#pragma unroll
                for (int j = 0; j < 4; j++) rrB[j] = csr[k0 + ((it + 1) << 3) + 2 * j];
                CONSU8(rrA, vv)
            }
            {
                unsigned int vv[4];
#pragma unroll
                for (int j = 0; j < 4; j++) vv[j] = sbase[(size_t)EDGE_S(rrB[j]) * 32];
                if (it + 2 < nfull) {
#pragma unroll
                    for (int j = 0; j < 4; j++) rrA[j] = csr[k0 + ((it + 2) << 3) + 2 * j];
                }
                CONSU8(rrB, vv)
            }
            it += 2;
        }
        if (it < nfull) {
            unsigned int vv[4];
#pragma unroll
            for (int j = 0; j < 4; j++) vv[j] = sbase[(size_t)EDGE_S(rrA[j]) * 32];
            CONSU8(rrA, vv)
        }
    }
    int t0 = nfull << 2;
    if (t0 < cnt) {
        unsigned int rrt[4], vv[4];
#pragma unroll
        for (int j = 0; j < 4; j++) {
            int t = t0 + j;
            rrt[j] = csr[t < cnt ? k0 + 2 * t : beg];
        }
#pragma unroll
        for (int j = 0; j < 4; j++) vv[j] = sbase[(size_t)EDGE_S(rrt[j]) * 32];
#pragma unroll
        for (int j = 0; j < 4; j++) {
            float we = (t0 + j < cnt) ? EDGE_W(rrt[j]) : 0.f;
            f32x2 lo = __builtin_amdgcn_cvt_pk_f32_fp8(vv[j], false);
            f32x2 hi = __builtin_amdgcn_cvt_pk_f32_fp8(vv[j], true);
            a0 = fmaf(we, lo.x, a0);
            a1 = fmaf(we, lo.y, a1);
            a2 = fmaf(we, hi.x, a2);
            a3 = fmaf(we, hi.y, a3);
        }
    }
#undef CONSU8
    a0 += __shfl_xor(a0, 32, 64);
    a1 += __shfl_xor(a1, 32, 64);
    a2 += __shfl_xor(a2, 32, 64);
    a3 += __shfl_xor(a3, 32, 64);
    if (lane < 32) {
        int m = lane >> 1, sb = 4 * (lane & 1);
        float av[4] = {a0, a1, a2, a3};
#pragma unroll
        for (int j = 0; j < 4; j++) {
            int L = (sb + j) * 16 + m;
            if (L >= 40 && L < 80) T2a[(size_t)i * 40 + (L - 40)] = f2bf(av[j]);
            else if (L >= 80 && L < 120) T8b[(size_t)i * 40 + (L - 80)] = pack_fp8x1(av[j]);
        }
    }
}

// ---------------- fused second-hop prop + log_softmax -----------------------
// 6 groups x 10 lanes, batch-of-4 per group + prefetch + masked final batch

__global__ __launch_bounds__(256) void lsm_prop_k(const unsigned short* __restrict__ Ub,
                                                  const unsigned short* __restrict__ T2a,
                                                  const unsigned char* __restrict__ T8b,
                                                  const int* __restrict__ rowptr,
                                                  const unsigned int* __restrict__ csr,
                                                  const float* __restrict__ dinv,
                                                  const float* __restrict__ b2,
                                                  float* __restrict__ out, int n) {
    int wave = threadIdx.x >> 6;
    int lane = threadIdx.x & 63;
    int i = blockIdx.x * 4 + wave;
    if (i >= n) return;
    int beg = rowptr[i], end = rowptr[i + 1];
    float di = dinv[i];
    int g = lane / 10;           // 0..6 (lanes 60..63 inactive)
    int c = lane - g * 10;       // 0..9
    bool act = lane < 60;
    const unsigned int* sb = (const unsigned int*)T8b + c;  // row stride 10 uints
    float a0 = 0.f, a1 = 0.f, a2 = 0.f, a3 = 0.f;
    if (lane < 10) {  // self term counted once (group 0)
        unsigned int sv = sb[(size_t)i * 10];
        float w = di * di;
        f32x2 lo = __builtin_amdgcn_cvt_pk_f32_fp8(sv, false);
        f32x2 hi = __builtin_amdgcn_cvt_pk_f32_fp8(sv, true);
        a0 = w * lo.x; a1 = w * lo.y; a2 = w * hi.x; a3 = w * hi.y;
    }

#define CONSLS(rr, vv)                                                        \
    _Pragma("unroll") for (int j = 0; j < 4; j++) {                           \
        float we = EDGE_W(rr[j]);                                             \
        f32x2 lo = __builtin_amdgcn_cvt_pk_f32_fp8(vv[j], false);             \
        f32x2 hi = __builtin_amdgcn_cvt_pk_f32_fp8(vv[j], true);              \
        a0 = fmaf(we, lo.x, a0);                                              \
        a1 = fmaf(we, lo.y, a1);                                              \
        a2 = fmaf(we, hi.x, a2);                                              \
        a3 = fmaf(we, hi.y, a3);                                              \
    }

    int k0 = beg + g;
    int cnt = (act && k0 < end) ? ((end - k0 + 5) / 6) : 0;  // edges this group owns
    int nfull = cnt >> 2;
    unsigned int rrA[4], rrB[4];
    if (nfull > 0) {
#pragma unroll
        for (int j = 0; j < 4; j++) rrA[j] = csr[k0 + 6 * j];
        int it = 0;
        while (it + 2 <= nfull) {
            {
                unsigned int vv[4];
#pragma unroll
                for (int j = 0; j < 4; j++) vv[j] = sb[(size_t)EDGE_S(rrA[j]) * 10];
#pragma unroll
                for (int j = 0; j < 4; j++) rrB[j] = csr[k0 + (it + 1) * 24 + 6 * j];
                CONSLS(rrA, vv)
            }
            {
                unsigned int vv[4];
#pragma unroll
                for (int j = 0; j < 4; j++) vv[j] = sb[(size_t)EDGE_S(rrB[j]) * 10];
                if (it + 2 < nfull) {
#pragma unroll
                    for (int j = 0; j < 4; j++) rrA[j] = csr[k0 + (it + 2) * 24 + 6 * j];
                }
                CONSLS(rrB, vv)
            }
            it += 2;
        }
        if (it < nfull) {
            unsigned int vv[4];
#pragma unroll
            for (int j = 0; j < 4; j++) vv[j] = sb[(size_t)EDGE_S(rrA[j]) * 10];
            CONSLS(rrA, vv)
        }
    }
    int t0 = nfull << 2;
    if (t0 < cnt) {
        unsigned int rrt[4], vv[4];
#pragma unroll
        for (int j = 0; j < 4; j++) {
            int t = t0 + j;
            rrt[j] = csr[t < cnt ? k0 + 6 * t : beg];
        }
#pragma unroll
        for (int j = 0; j < 4; j++) vv[j] = sb[(size_t)EDGE_S(rrt[j]) * 10];
#pragma unroll
        for (int j = 0; j < 4; j++) {
            float we = (t0 + j < cnt) ? EDGE_W(rrt[j]) : 0.f;
            f32x2 lo = __builtin_amdgcn_cvt_pk_f32_fp8(vv[j], false);
            f32x2 hi = __builtin_amdgcn_cvt_pk_f32_fp8(vv[j], true);
            a0 = fmaf(we, lo.x, a0);
            a1 = fmaf(we, lo.y, a1);
            a2 = fmaf(we, hi.x, a2);
            a3 = fmaf(we, hi.y, a3);
        }
    }
#undef CONSLS
    // reduce the 6 group partials into lanes 0..9 (results valid there only)
    float r0s = a0, r1s = a1, r2s = a2, r3s = a3;
#pragma unroll
    for (int g2 = 1; g2 < 6; g2++) {
        r0s += __shfl(a0, lane + 10 * g2, 64);
        r1s += __shfl(a1, lane + 10 * g2, 64);
        r2s += __shfl(a2, lane + 10 * g2, 64);
        r3s += __shfl(a3, lane + 10 * g2, 64);
    }
    // redistribute: lane j1=lane+64 needs col idx=j1-80 from lane idx>>2, comp idx&3
    int j1 = lane + 64;
    int idx = j1 - 80;
    int srcl = (idx < 0) ? 0 : (idx >> 2);
    float s0v = __shfl(r0s, srcl, 64);
    float s1v = __shfl(r1s, srcl, 64);
    float s2v = __shfl(r2s, srcl, 64);
    float s3v = __shfl(r3s, srcl, 64);
    int comp = idx & 3;
    float pv = (comp == 0) ? s0v : (comp == 1) ? s1v : (comp == 2) ? s2v : s3v;
    float v0, v1;
    {
        int j = lane;  // 0..63
        float v = (j >= 40) ? bf2f(T2a[(size_t)i * 40 + (j - 40)]) : bf2f(Ub[(size_t)i * L2WP + j]);
        v0 = v + b2[j];
    }
    if (j1 < 120) {
        float v = (j1 < 80) ? bf2f(T2a[(size_t)i * 40 + (j1 - 40)]) : pv;
        v1 = v + b2[j1];
    } else {
        v1 = -INFINITY;
    }
    float m = fmaxf(v0, v1);
    for (int off = 32; off; off >>= 1) m = fmaxf(m, __shfl_xor(m, off, 64));
    float s = expf(v0 - m) + ((j1 < 120) ? expf(v1 - m) : 0.f);
    for (int off = 32; off; off >>= 1) s += __shfl_xor(s, off, 64);
    float ls = logf(s) + m;
    out[(size_t)i * 120 + lane] = v0 - ls;
    if (j1 < 120) out[(size_t)i * 120 + j1] = v1 - ls;
}

// ---------------- launch ----------------

static inline size_t align256(size_t x) { return (x + 255) & ~(size_t)255; }

extern "C" void kernel_launch(void* const* d_in, const int* in_sizes, int n_in,
                              void* d_out, int out_size, void* d_ws, size_t ws_size,
                              hipStream_t stream) {
    const float* x = (const float*)d_in[0];
    const int* ei = (const int*)d_in[1];
    const float* W1_0 = (const float*)d_in[2];
    const float* W1_1 = (const float*)d_in[3];
    const float* W1_2 = (const float*)d_in[4];
    const float* b1 = (const float*)d_in[5];
    const float* W2_0 = (const float*)d_in[6];
    const float* W2_1 = (const float*)d_in[7];
    const float* W2_2 = (const float*)d_in[8];
    const float* b2 = (const float*)d_in[9];
    float* out = (float*)d_out;

    const int n = N_NODES;
    const int E = in_sizes[1] / 2;
    const int nb = (n + 255) / 256;
    const int nbe4 = ((E + 3) / 4 + 255) / 256;
    const int n2 = NBUK * NBLK1;
    const int nb2 = (n2 + 255) / 256;

    char* p = (char*)d_ws;
    size_t off = 0;
    auto alloc = [&](size_t bytes) {
        void* r = p + off;
        off = align256(off + bytes);
        return r;
    };
    int* flag = (int*)alloc(4);
    int* cnt = (int*)alloc((size_t)n * 4);
    int* rowptr = (int*)alloc((size_t)(n + 1) * 4);
    int* bsum = (int*)alloc((size_t)nb * 4);
    float* dinv = (float*)alloc((size_t)n * 4);
    unsigned int* csr = (unsigned int*)alloc((size_t)E * 4);
    int* cnt2 = (int*)alloc((size_t)n2 * 4);
    int* off2 = (int*)alloc((size_t)n2 * 4);
    int* bsum2 = (int*)alloc((size_t)nb2 * 4);
    int* tot2 = (int*)alloc(4);
    unsigned int* stage = (unsigned int*)alloc((size_t)E * 4);
    unsigned short* Bp1 = (unsigned short*)alloc((size_t)N1PACK * 2);
    unsigned short* Bp2 = (unsigned short*)alloc((size_t)N2PACK * 2);
    unsigned short* Hb = (unsigned short*)alloc((size_t)n * L1W * 2);
    unsigned char* Y8 = (unsigned char*)alloc((size_t)n * 256);
    unsigned char* T8 = (unsigned char*)alloc((size_t)n * 128);
    unsigned short* Ub = (unsigned short*)alloc((size_t)n * L2WP * 2);
    unsigned char* U8 = (unsigned char*)alloc((size_t)n * 128);
    unsigned short* T2a = (unsigned short*)alloc((size_t)n * C_OUT * 2);
    unsigned char* T8b = (unsigned char*)alloc((size_t)n * C_OUT);
    (void)ws_size;

    // 0. edge dtype detect
    detect_k<<<1, 256, 0, stream>>>(ei, flag);

    // 1. per-node degree + rowptr (+dinv fused)
    hipMemsetAsync(cnt, 0, (size_t)n * 4, stream);
    hist_k<<<nbe4, 256, 0, stream>>>(ei, flag, cnt, E);
    scan1_k<<<nb, 256, 0, stream>>>(cnt, bsum, n);
    scan2_k<<<1, 256, 0, stream>>>(bsum, rowptr + n, nb);
    scan3_k<<<nb, 256, 0, stream>>>(cnt, bsum, rowptr, dinv, n);

    // 2. two-phase binned scatter -> csr
    hist2_k<<<NBLK1, 256, 0, stream>>>(ei, flag, cnt2, E);
    scan1_k<<<nb2, 256, 0, stream>>>(cnt2, bsum2, n2);
    scan2_k<<<1, 256, 0, stream>>>(bsum2, tot2, nb2);
    scan3_k<<<nb2, 256, 0, stream>>>(cnt2, bsum2, off2, (float*)nullptr, n2);
    stage_k<<<NBLK1, 256, 0, stream>>>(ei, flag, off2, stage, E);
    scatter2_k<<<NBUK, 256, 0, stream>>>(stage, off2, rowptr, dinv, csr, E, n);

    // 3. weight packing (merged)
    pack_k<<<(N1PACK + N2PACK + 255) / 256, 256, 0, stream>>>(W1_0, W1_1, W1_2,
                                                              W2_0, W2_1, W2_2, Bp1, Bp2);

    // 4. layer 1 GEMM (z1 -> Hb bf16, y2 -> Y8 fp8 transposed)
    mgemm1_k<<<(n + 63) / 64, 256, 0, stream>>>(x, Bp1, b1, Hb, Y8, n);
    prop256f_k<<<(n + 3) / 4, 256, 0, stream>>>(Y8, Hb, T8, rowptr, csr, dinv, b1, n);
    prop128f_k<<<(n + 3) / 4, 256, 0, stream>>>(T8, Hb, rowptr, csr, dinv, b1, n);

    // 5. layer 2 GEMM -> Ub bf16 (cols<48) + U8 fp8 (1 line/row)
    mgemm2_k<<<(n + 63) / 64, 256, 0, stream>>>(Hb, Bp2, Ub, U8, n);
    propU8_k<<<(n + 3) / 4, 256, 0, stream>>>(U8, T2a, T8b, rowptr, csr, dinv, n);

    // 6. fused second hop + log_softmax
    lsm_prop_k<<<(n + 3) / 4, 256, 0, stream>>>(Ub, T2a, T8b, rowptr, csr, dinv, b2, out, n);
}

// Round 6
// 344.090 us; speedup vs baseline: 1.1321x; 1.1321x over previous
//
#include <hip/hip_runtime.h>
#include <hip/hip_bf16.h>
#include <math.h>

#define N_NODES 50000
#define F_IN 256
#define H1 128
#define C_OUT 40
#define L1W 384   // 3*H1
#define L2W 120   // 3*C_OUT
#define L2WP 128  // padded
#define NBUK 196  // ceil(50000/256) dst buckets of 256 nodes
#define NBLK1 256 // phase-1 blocks

typedef __attribute__((ext_vector_type(8))) short short8;
typedef __attribute__((ext_vector_type(4))) float f32x4;
typedef __attribute__((ext_vector_type(2))) float f32x2;

typedef __attribute__((address_space(1))) const unsigned int gu32;
typedef __attribute__((address_space(3))) unsigned int lu32;

__device__ __forceinline__ void g2l16(const void* g, void* l) {
    __builtin_amdgcn_global_load_lds((gu32*)g, (lu32*)l, 16, 0, 0);
}

__device__ inline unsigned short f2bf(float f) {
    union { float f; unsigned int u; } x;
    x.f = f;
    unsigned int u = x.u;
    return (unsigned short)((u + 0x7FFF + ((u >> 16) & 1)) >> 16);
}
__device__ inline float bf2f(unsigned short u) {
    union { unsigned int u; float f; } x;
    x.u = (unsigned int)u << 16;
    return x.f;
}
__device__ inline unsigned int pack_fp8x4(float a, float b, float c, float d) {
    int v = 0;
    v = __builtin_amdgcn_cvt_pk_fp8_f32(a, b, v, false);  // bytes 0,1
    v = __builtin_amdgcn_cvt_pk_fp8_f32(c, d, v, true);   // bytes 2,3
    return (unsigned int)v;
}
__device__ inline unsigned short pack_fp8x2(float a, float b) {
    return (unsigned short)(__builtin_amdgcn_cvt_pk_fp8_f32(a, b, 0, false) & 0xFFFF);
}
__device__ inline unsigned char pack_fp8x1(float a) {
    return (unsigned char)(__builtin_amdgcn_cvt_pk_fp8_f32(a, a, 0, false) & 0xFF);
}
// decode 4B edge record {w:bf16:16 | src:16}
#define EDGE_S(r) ((int)((r) & 0xFFFFu))
#define EDGE_W(r) bf2f((unsigned short)((r) >> 16))

// ---------------- edge-index dtype detection --------------------------------

__global__ void detect_k(const int* __restrict__ ei, int* __restrict__ flag) {
    __shared__ int any;
    if (threadIdx.x == 0) any = 0;
    __syncthreads();
    int v = 0;
    for (int r = 0; r < 4; r++) {
        int e = threadIdx.x + r * 256;
        v |= ei[e * 2 + 1];
    }
    if (v != 0) atomicOr(&any, 1);
    __syncthreads();
    if (threadIdx.x == 0) *flag = any;  // 1 => int32 layout, 0 => int64
}

// ---------------- per-node degree histogram ---------------------------------

__global__ void hist_k(const int* __restrict__ ei, const int* __restrict__ flag,
                       int* __restrict__ cnt, int E) {
    int base = (blockIdx.x * 256 + threadIdx.x) * 4;
    if (base >= E) return;
    if (base + 4 <= E) {
        int d0, d1, d2, d3;
        if (*flag) {
            int4 dv = *(const int4*)(ei + E + base);
            d0 = dv.x; d1 = dv.y; d2 = dv.z; d3 = dv.w;
        } else {
            const long long* e64 = (const long long*)ei;
            longlong2 a = *(const longlong2*)(e64 + E + base);
            longlong2 b = *(const longlong2*)(e64 + E + base + 2);
            d0 = (int)a.x; d1 = (int)a.y; d2 = (int)b.x; d3 = (int)b.y;
        }
        atomicAdd(&cnt[d0], 1);
        atomicAdd(&cnt[d1], 1);
        atomicAdd(&cnt[d2], 1);
        atomicAdd(&cnt[d3], 1);
    } else {
        for (int e = base; e < E; e++) {
            int d = (*flag) ? ei[E + e] : (int)((const long long*)ei)[E + e];
            atomicAdd(&cnt[d], 1);
        }
    }
}

// ---------------- generic 3-level exclusive scan ----------------------------

__global__ __launch_bounds__(256) void scan1_k(const int* __restrict__ cnt,
                                               int* __restrict__ bsum, int n) {
    int t = threadIdx.x;
    int i = blockIdx.x * 256 + t;
    int v = (i < n) ? cnt[i] : 0;
    for (int off = 32; off; off >>= 1) v += __shfl_down(v, off, 64);
    __shared__ int ws[4];
    if ((t & 63) == 0) ws[t >> 6] = v;
    __syncthreads();
    if (t == 0) bsum[blockIdx.x] = ws[0] + ws[1] + ws[2] + ws[3];
}

__global__ __launch_bounds__(256) void scan2_k(int* __restrict__ bsum,
                                               int* __restrict__ btot, int nb) {
    __shared__ int s[256];
    int t = threadIdx.x;
    int v = (t < nb) ? bsum[t] : 0;
    s[t] = v;
    __syncthreads();
    for (int off = 1; off < 256; off <<= 1) {
        int u = (t >= off) ? s[t - off] : 0;
        __syncthreads();
        s[t] += u;
        __syncthreads();
    }
    if (t < nb) bsum[t] = s[t] - v;  // exclusive
    if (t == nb - 1) *btot = s[t];
}

// scan3 + optional dinv fusion (dinv != nullptr only for the node scan)
__global__ __launch_bounds__(256) void scan3_k(const int* __restrict__ cnt,
                                               const int* __restrict__ bsum,
                                               int* __restrict__ rowptr,
                                               float* __restrict__ dinv, int n) {
    __shared__ int s[256];
    int t = threadIdx.x;
    int i = blockIdx.x * 256 + t;
    int v = (i < n) ? cnt[i] : 0;
    s[t] = v;
    __syncthreads();
    for (int off = 1; off < 256; off <<= 1) {
        int u = (t >= off) ? s[t - off] : 0;
        __syncthreads();
        s[t] += u;
        __syncthreads();
    }
    if (i < n) {
        rowptr[i] = s[t] - v + bsum[blockIdx.x];
        if (dinv) dinv[i] = rsqrtf((float)v + 1.0f);
    }
}

// ---------------- two-phase binned scatter ----------------------------------

__global__ __launch_bounds__(256) void hist2_k(const int* __restrict__ ei,
                                               const int* __restrict__ flag,
                                               int* __restrict__ cnt2, int E) {
    __shared__ int lcnt[NBUK];
    int t = threadIdx.x, blk = blockIdx.x;
    for (int j = t; j < NBUK; j += 256) lcnt[j] = 0;
    __syncthreads();
    int chunk = (E + NBLK1 - 1) / NBLK1;
    int beg = blk * chunk, end = min(beg + chunk, E);
    bool i32 = (*flag) != 0;
    const long long* e64 = (const long long*)ei;
    for (int e = beg + t; e < end; e += 256) {
        int d = i32 ? ei[E + e] : (int)e64[E + e];
        atomicAdd(&lcnt[d >> 8], 1);
    }
    __syncthreads();
    for (int j = t; j < NBUK; j += 256) cnt2[j * NBLK1 + blk] = lcnt[j];  // bucket-major
}

__global__ __launch_bounds__(256) void stage_k(const int* __restrict__ ei,
                                               const int* __restrict__ flag,
                                               const int* __restrict__ off2,
                                               unsigned int* __restrict__ stage, int E) {
    __shared__ int lcur[NBUK];
    int t = threadIdx.x, blk = blockIdx.x;
    for (int j = t; j < NBUK; j += 256) lcur[j] = off2[j * NBLK1 + blk];
    __syncthreads();
    int chunk = (E + NBLK1 - 1) / NBLK1;
    int beg = blk * chunk, end = min(beg + chunk, E);
    bool i32 = (*flag) != 0;
    const long long* e64 = (const long long*)ei;
    for (int e = beg + t; e < end; e += 256) {
        int s, d;
        if (i32) { s = ei[e]; d = ei[E + e]; }
        else { s = (int)e64[e]; d = (int)e64[E + e]; }
        int b = d >> 8;
        int pos = atomicAdd(&lcur[b], 1);
        stage[pos] = ((unsigned int)(d & 255) << 16) | (unsigned int)s;
    }
}

__global__ __launch_bounds__(256) void scatter2_k(const unsigned int* __restrict__ stage,
                                                  const int* __restrict__ off2,
                                                  const int* __restrict__ rowptr,
                                                  const float* __restrict__ dinv,
                                                  unsigned int* __restrict__ csr,
                                                  int E, int n) {
    __shared__ int lfill[256];
    int b = blockIdx.x, t = threadIdx.x;
    int node0 = b << 8;
    int node = node0 + t;
    lfill[t] = (node < n) ? rowptr[node] : 0;
    __syncthreads();
    int segBeg = off2[b * NBLK1];
    int segEnd = (b == NBUK - 1) ? E : off2[(b + 1) * NBLK1];
    for (int e = segBeg + t; e < segEnd; e += 256) {
        unsigned int rec = stage[e];
        int dl = rec >> 16;
        int s = rec & 0xFFFF;
        int d = node0 + dl;
        float w = dinv[s] * dinv[d];
        int pos = atomicAdd(&lfill[dl], 1);
        csr[pos] = ((unsigned int)f2bf(w) << 16) | (unsigned int)s;
    }
}

// ---------------- weight packing (bf16, B-fragment layout), merged ----------
// Tile-internal layout: within each 512-short tile: off = kq*128 + m*8 + kk
// (col = s*16+m, k = kt*32 + kq*8 + kk) -> lane l = kq*16+m reads/writes
// shorts l*8..l*8+7, i.e. G2L's lane-linear 16B destination exactly.

#define N1PACK ((F_IN / 32) * L1W * 32)
#define N2PACK ((L1W / 32) * L2WP * 32)

__global__ void pack_k(const float* __restrict__ w10, const float* __restrict__ w11,
                       const float* __restrict__ w12, const float* __restrict__ w20,
                       const float* __restrict__ w21, const float* __restrict__ w22,
                       unsigned short* __restrict__ Bp1, unsigned short* __restrict__ Bp2) {
    int idx = blockIdx.x * 256 + threadIdx.x;
    if (idx < N1PACK) {
        int kt = idx / (L1W * 32);
        int t = idx % (L1W * 32);
        int s = t >> 9;
        int u = t & 511;
        int kq = u >> 7, m = (u >> 3) & 15, kk = u & 7;
        int col = s * 16 + m;
        int k = kt * 32 + kq * 8 + kk;
        int p = col >> 7, c = col & 127;
        const float* w = (p == 0) ? w10 : (p == 1) ? w11 : w12;
        Bp1[idx] = f2bf(w[k * H1 + c]);
    } else if (idx < N1PACK + N2PACK) {
        int j = idx - N1PACK;
        int kt = j / (L2WP * 32);
        int t = j % (L2WP * 32);
        int s = t >> 9;
        int u = t & 511;
        int kq = u >> 7, m = (u >> 3) & 15, kk = u & 7;
        int col = s * 16 + m;
        int k = kt * 32 + kq * 8 + kk;
        unsigned short v = 0;
        if (col < L2W) {
            int p = col / 40, c = col % 40;
            const float* w = (p == 0) ? w20 : (p == 1) ? w21 : w22;
            v = f2bf(w[k * C_OUT + c]);
        }
        Bp2[j] = v;
    }
}

// ---------------- layer-1 GEMM: counted-vmcnt pipeline, raw barriers --------
// Block = 64 rows x 384 cols, 4 waves; wave = 16 rows (full-K A preload,
// areg[8]) x all 24 N-tiles. B staged once per block: wave w G2Ls tiles
// 6w..6w+5 into a shared 2-slot LDS buffer. Raw s_barrier (no vmcnt(0)
// drain) + per-wave counted vmcnt(6): after entry the vmem queue holds ONLY
// G2L ops, so vmcnt(6) = "my slot-kt tiles landed" with kt+1 still in flight.

__global__ __launch_bounds__(256, 2) void mgemm1_k(const float* __restrict__ A,
                                                   const unsigned short* __restrict__ Bp,
                                                   const float* __restrict__ b1,
                                                   unsigned short* __restrict__ Hb,
                                                   unsigned char* __restrict__ Y8, int N) {
    __shared__ unsigned short Bls[2][L1W * 32];  // 2 slots x 24 KB
    int tid = threadIdx.x;
    int w = tid >> 6, lane = tid & 63;
    int m = lane & 15, kq = lane >> 4;
    int row0 = blockIdx.x * 64 + w * 16;
    int arow = row0 + m;
    if (arow >= N) arow = N - 1;  // clamped duplicate; stores guarded
    const float* Ap = A + (size_t)arow * F_IN + kq * 8;
    const char* srcb = (const char*)Bp + (size_t)(w * 6) * 1024 + (size_t)lane * 16;

    // 1) issue ALL A loads first (16 dwordx4 in flight)
    float4 at0[8], at1[8];
#pragma unroll
    for (int kt = 0; kt < 8; kt++) {
        at0[kt] = *(const float4*)(Ap + kt * 32);
        at1[kt] = *(const float4*)(Ap + kt * 32 + 4);
    }
    // 2) issue G2L for slots 0 and 1 (wave w: tiles 6w..6w+5)
#pragma unroll
    for (int j = 0; j < 6; j++) g2l16(srcb + j * 1024, &Bls[0][(w * 6 + j) * 512]);
#pragma unroll
    for (int j = 0; j < 6; j++) g2l16(srcb + 24576 + j * 1024, &Bls[1][(w * 6 + j) * 512]);
    // 3) convert A -> bf16 (compiler waits the A loads; G2L stay outstanding)
    short8 areg[8];
#pragma unroll
    for (int kt = 0; kt < 8; kt++) {
        float4 u = at0[kt], v = at1[kt];
        short8 a;
        a[0] = (short)f2bf(u.x); a[1] = (short)f2bf(u.y);
        a[2] = (short)f2bf(u.z); a[3] = (short)f2bf(u.w);
        a[4] = (short)f2bf(v.x); a[5] = (short)f2bf(v.y);
        a[6] = (short)f2bf(v.z); a[7] = (short)f2bf(v.w);
        areg[kt] = a;
    }

    f32x4 acc[24];
#pragma unroll
    for (int s = 0; s < 24; s++) acc[s] = (f32x4){0.f, 0.f, 0.f, 0.f};

#pragma unroll
    for (int kt = 0; kt < 8; kt++) {
        // my 6 tiles of slot kt landed (G2L(kt+1) still in flight)
        if (kt < 7) { asm volatile("s_waitcnt vmcnt(6)" ::: "memory"); }
        else        { asm volatile("s_waitcnt vmcnt(0)" ::: "memory"); }
        __builtin_amdgcn_sched_barrier(0);
        __builtin_amdgcn_s_barrier();  // all waves' tiles for slot kt landed
        const unsigned short* Bbuf = Bls[kt & 1];
#pragma unroll
        for (int c = 0; c < 4; c++) {
            short8 bf[6];
#pragma unroll
            for (int j = 0; j < 6; j++)
                bf[j] = *(const short8*)(&Bbuf[(c * 6 + j) * 512 + lane * 8]);
            asm volatile("s_waitcnt lgkmcnt(0)" ::: "memory");
            __builtin_amdgcn_sched_barrier(0);
            if (c == 3) {
                __builtin_amdgcn_s_barrier();  // all reads of slot kt retired
                if (kt < 6) {                  // refill freed slot
#pragma unroll
                    for (int j = 0; j < 6; j++)
                        g2l16(srcb + (size_t)(kt + 2) * 24576 + j * 1024,
                              &Bls[kt & 1][(w * 6 + j) * 512]);
                }
            }
#pragma unroll
            for (int j = 0; j < 6; j++)
                acc[c * 6 + j] = __builtin_amdgcn_mfma_f32_16x16x32_bf16(
                    areg[kt], bf[j], acc[c * 6 + j], 0, 0, 0);
        }
    }

    int crow = row0 + kq * 4;
#pragma unroll
    for (int s = 0; s < 8; s++) {
        int col = s * 16 + m;
        float bias = b1[col];
#pragma unroll
        for (int r2 = 0; r2 < 4; r2++) {
            int row = crow + r2;
            if (row < N) Hb[(size_t)row * L1W + col] = f2bf(fmaxf(acc[s][r2] + bias, 0.f));
        }
    }
#pragma unroll
    for (int r2 = 0; r2 < 4; r2++) {
        int row = crow + r2;
        if (row < N) {
            uint4 u;
            u.x = pack_fp8x4(acc[8][r2], acc[9][r2], acc[10][r2], acc[11][r2]);
            u.y = pack_fp8x4(acc[12][r2], acc[13][r2], acc[14][r2], acc[15][r2]);
            u.z = pack_fp8x4(acc[16][r2], acc[17][r2], acc[18][r2], acc[19][r2]);
            u.w = pack_fp8x4(acc[20][r2], acc[21][r2], acc[22][r2], acc[23][r2]);
            *(uint4*)(Y8 + (size_t)row * 256 + m * 16) = u;
        }
    }
}

// ---------------- layer-2 GEMM: same counted-vmcnt structure ----------------
// Block = 64 rows x 128 cols; wave = 16 rows x 8 tiles; wave w stages 2 tiles.

__global__ __launch_bounds__(256, 3) void mgemm2_k(const unsigned short* __restrict__ A,
                                                   const unsigned short* __restrict__ Bp,
                                                   unsigned short* __restrict__ Ub,
                                                   unsigned char* __restrict__ U8, int N) {
    __shared__ unsigned short Bls[2][L2WP * 32];  // 2 slots x 8 KB
    int tid = threadIdx.x;
    int w = tid >> 6, lane = tid & 63;
    int m = lane & 15, kq = lane >> 4;
    int row0 = blockIdx.x * 64 + w * 16;
    int arow = row0 + m;
    if (arow >= N) arow = N - 1;
    const unsigned short* Ap = A + (size_t)arow * L1W + kq * 8;
    const char* srcb = (const char*)Bp + (size_t)(w * 2) * 1024 + (size_t)lane * 16;

    // issue ALL A loads (12 x 16B), then G2L slots 0,1 (2 tiles/wave each)
    short8 areg[12];
#pragma unroll
    for (int kt = 0; kt < 12; kt++) areg[kt] = *(const short8*)(Ap + kt * 32);
#pragma unroll
    for (int j = 0; j < 2; j++) g2l16(srcb + j * 1024, &Bls[0][(w * 2 + j) * 512]);
#pragma unroll
    for (int j = 0; j < 2; j++) g2l16(srcb + 8192 + j * 1024, &Bls[1][(w * 2 + j) * 512]);

    f32x4 acc[8];
#pragma unroll
    for (int s = 0; s < 8; s++) acc[s] = (f32x4){0.f, 0.f, 0.f, 0.f};

#pragma unroll
    for (int kt = 0; kt < 12; kt++) {
        if (kt < 11) { asm volatile("s_waitcnt vmcnt(2)" ::: "memory"); }
        else         { asm volatile("s_waitcnt vmcnt(0)" ::: "memory"); }
        __builtin_amdgcn_sched_barrier(0);
        __builtin_amdgcn_s_barrier();
        const unsigned short* Bbuf = Bls[kt & 1];
        short8 bf[8];
#pragma unroll
        for (int j = 0; j < 8; j++)
            bf[j] = *(const short8*)(&Bbuf[j * 512 + lane * 8]);
        asm volatile("s_waitcnt lgkmcnt(0)" ::: "memory");
        __builtin_amdgcn_sched_barrier(0);
        __builtin_amdgcn_s_barrier();  // all reads of slot kt retired
        if (kt < 10) {
#pragma unroll
            for (int j = 0; j < 2; j++)
                g2l16(srcb + (size_t)(kt + 2) * 8192 + j * 1024,
                      &Bls[kt & 1][(w * 2 + j) * 512]);
        }
#pragma unroll
        for (int j = 0; j < 8; j++)
            acc[j] = __builtin_amdgcn_mfma_f32_16x16x32_bf16(areg[kt], bf[j], acc[j], 0, 0, 0);
    }

    int crow = row0 + kq * 4;
#pragma unroll
    for (int s = 0; s < 3; s++) {
        int col = s * 16 + m;
#pragma unroll
        for (int r2 = 0; r2 < 4; r2++) {
            int row = crow + r2;
            if (row < N) Ub[(size_t)row * L2WP + col] = f2bf(acc[s][r2]);
        }
    }
#pragma unroll
    for (int r2 = 0; r2 < 4; r2++) {
        int row = crow + r2;
        if (row < N) {
            uint2 u;
            u.x = pack_fp8x4(acc[0][r2], acc[1][r2], acc[2][r2], acc[3][r2]);
            u.y = pack_fp8x4(acc[4][r2], acc[5][r2], acc[6][r2], acc[7][r2]);
            *(uint2*)(U8 + (size_t)row * 128 + m * 8) = u;
        }
    }
}

// ---------------- fused width-256 fp8 prop over Y8 --------------------------
// pipelined: ping-pong csr prefetch (rrA/rrB) + masked final batch (no serial tail)

__global__ __launch_bounds__(256) void prop256f_k(const unsigned char* __restrict__ Y8,
                                                  unsigned short* __restrict__ Hb,
                                                  unsigned char* __restrict__ T8,
                                                  const int* __restrict__ rowptr,
                                                  const unsigned int* __restrict__ csr,
                                                  const float* __restrict__ dinv,
                                                  const float* __restrict__ b1, int n) {
    int wave = threadIdx.x >> 6, lane = threadIdx.x & 63;
    int i = blockIdx.x * 4 + wave;
    if (i >= n) return;
    int beg = rowptr[i], end = rowptr[i + 1];
    float di = dinv[i];
    const unsigned int* sbase = (const unsigned int*)Y8 + lane;  // row stride 64 uints
    unsigned int sv = sbase[(size_t)i * 64];
    float w = di * di;
    f32x2 slo = __builtin_amdgcn_cvt_pk_f32_fp8(sv, false);
    f32x2 shi = __builtin_amdgcn_cvt_pk_f32_fp8(sv, true);
    float a0 = w * slo.x, a1 = w * slo.y, a2 = w * shi.x, a3 = w * shi.y;

#define CONS256(rr, vv)                                                       \
    _Pragma("unroll") for (int e = 0; e < 8; e++) {                           \
        float we = EDGE_W(rr[e]);                                             \
        f32x2 lo = __builtin_amdgcn_cvt_pk_f32_fp8(vv[e], false);             \
        f32x2 hi = __builtin_amdgcn_cvt_pk_f32_fp8(vv[e], true);              \
        a0 = fmaf(we, lo.x, a0);                                              \
        a1 = fmaf(we, lo.y, a1);                                              \
        a2 = fmaf(we, hi.x, a2);                                              \
        a3 = fmaf(we, hi.y, a3);                                              \
    }

    int nfull = (end - beg) >> 3;
    unsigned int rrA[8], rrB[8];
    if (nfull > 0) {
#pragma unroll
        for (int e = 0; e < 8; e++) rrA[e] = csr[beg + e];
        int it = 0;
        while (it + 2 <= nfull) {
            {
                unsigned int vv[8];
#pragma unroll
                for (int e = 0; e < 8; e++) vv[e] = sbase[(size_t)EDGE_S(rrA[e]) * 64];
#pragma unroll
                for (int e = 0; e < 8; e++) rrB[e] = csr[beg + ((it + 1) << 3) + e];
                CONS256(rrA, vv)
            }
            {
                unsigned int vv[8];
#pragma unroll
                for (int e = 0; e < 8; e++) vv[e] = sbase[(size_t)EDGE_S(rrB[e]) * 64];
                if (it + 2 < nfull) {
#pragma unroll
                    for (int e = 0; e < 8; e++) rrA[e] = csr[beg + ((it + 2) << 3) + e];
                }
                CONS256(rrB, vv)
            }
            it += 2;
        }
        if (it < nfull) {  // odd last full batch (in rrA)
            unsigned int vv[8];
#pragma unroll
            for (int e = 0; e < 8; e++) vv[e] = sbase[(size_t)EDGE_S(rrA[e]) * 64];
            CONS256(rrA, vv)
        }
    }
    int k = beg + (nfull << 3);
    if (k < end) {  // masked final batch: parallel loads, zeroed weights OOB
        unsigned int rrt[8];
#pragma unroll
        for (int e = 0; e < 8; e++) {
            int idx = k + e;
            rrt[e] = csr[idx < end ? idx : beg];
        }
        unsigned int vv[8];
#pragma unroll
        for (int e = 0; e < 8; e++) vv[e] = sbase[(size_t)EDGE_S(rrt[e]) * 64];
#pragma unroll
        for (int e = 0; e < 8; e++) {
            float we = (k + e < end) ? EDGE_W(rrt[e]) : 0.f;
            f32x2 lo = __builtin_amdgcn_cvt_pk_f32_fp8(vv[e], false);
            f32x2 hi = __builtin_amdgcn_cvt_pk_f32_fp8(vv[e], true);
            a0 = fmaf(we, lo.x, a0);
            a1 = fmaf(we, lo.y, a1);
            a2 = fmaf(we, hi.x, a2);
            a3 = fmaf(we, hi.y, a3);
        }
    }
#undef CONS256
    int m = lane >> 2, jj = lane & 3;
    if (jj < 2) {  // z1: logical cols L_j = (4*jj+j)*16 + m
        float av[4] = {a0, a1, a2, a3};
#pragma unroll
        for (int j = 0; j < 4; j++) {
            int L = (4 * jj + j) * 16 + m;
            Hb[(size_t)i * L1W + 128 + L] = f2bf(fmaxf(av[j] + b1[128 + L], 0.f));
        }
    } else {       // t2 -> T8 phys = m*8 + 4*(jj-2)
        unsigned int o = pack_fp8x4(a0, a1, a2, a3);
        *(unsigned int*)(T8 + (size_t)i * 128 + m * 8 + 4 * (jj - 2)) = o;
    }
}

// ---------------- width-128 fp8 prop: Hb[:,256:384] = relu(P(T8)+b1) --------

__global__ __launch_bounds__(256) void prop128f_k(const unsigned char* __restrict__ T8,
                                                  unsigned short* __restrict__ Hb,
                                                  const int* __restrict__ rowptr,
                                                  const unsigned int* __restrict__ csr,
                                                  const float* __restrict__ dinv,
                                                  const float* __restrict__ b1, int n) {
    int wave = threadIdx.x >> 6, lane = threadIdx.x & 63;
    int i = blockIdx.x * 4 + wave;
    if (i >= n) return;
    int beg = rowptr[i], end = rowptr[i + 1];
    float di = dinv[i];
    const unsigned short* sbase = (const unsigned short*)T8 + lane;  // row stride 64
    unsigned int sv = sbase[(size_t)i * 64];
    float w = di * di;
    f32x2 sd = __builtin_amdgcn_cvt_pk_f32_fp8(sv, false);
    float a0 = w * sd.x, a1 = w * sd.y;

#define CONS128(rr, vv)                                                       \
    _Pragma("unroll") for (int e = 0; e < 8; e++) {                           \
        float we = EDGE_W(rr[e]);                                             \
        f32x2 d = __builtin_amdgcn_cvt_pk_f32_fp8(vv[e], false);              \
        a0 = fmaf(we, d.x, a0);                                               \
        a1 = fmaf(we, d.y, a1);                                               \
    }

    int nfull = (end - beg) >> 3;
    unsigned int rrA[8], rrB[8];
    if (nfull > 0) {
#pragma unroll
        for (int e = 0; e < 8; e++) rrA[e] = csr[beg + e];
        int it = 0;
        while (it + 2 <= nfull) {
            {
                unsigned int vv[8];
#pragma unroll
                for (int e = 0; e < 8; e++) vv[e] = sbase[(size_t)EDGE_S(rrA[e]) * 64];
#pragma unroll
                for (int e = 0; e < 8; e++) rrB[e] = csr[beg + ((it + 1) << 3) + e];
                CONS128(rrA, vv)
            }
            {
                unsigned int vv[8];
#pragma unroll
                for (int e = 0; e < 8; e++) vv[e] = sbase[(size_t)EDGE_S(rrB[e]) * 64];
                if (it + 2 < nfull) {
#pragma unroll
                    for (int e = 0; e < 8; e++) rrA[e] = csr[beg + ((it + 2) << 3) + e];
                }
                CONS128(rrB, vv)
            }
            it += 2;
        }
        if (it < nfull) {
            unsigned int vv[8];
#pragma unroll
            for (int e = 0; e < 8; e++) vv[e] = sbase[(size_t)EDGE_S(rrA[e]) * 64];
            CONS128(rrA, vv)
        }
    }
    int k = beg + (nfull << 3);
    if (k < end) {
        unsigned int rrt[8];
#pragma unroll
        for (int e = 0; e < 8; e++) {
            int idx = k + e;
            rrt[e] = csr[idx < end ? idx : beg];
        }
        unsigned int vv[8];
#pragma unroll
        for (int e = 0; e < 8; e++) vv[e] = sbase[(size_t)EDGE_S(rrt[e]) * 64];
#pragma unroll
        for (int e = 0; e < 8; e++) {
            float we = (k + e < end) ? EDGE_W(rrt[e]) : 0.f;
            f32x2 d = __builtin_amdgcn_cvt_pk_f32_fp8(vv[e], false);
            a0 = fmaf(we, d.x, a0);
            a1 = fmaf(we, d.y, a1);
        }
    }
#undef CONS128
    int m = lane >> 2, u0 = (2 * lane) & 7;
    int L0 = u0 * 16 + m, L1 = (u0 + 1) * 16 + m;
    Hb[(size_t)i * L1W + 256 + L0] = f2bf(fmaxf(a0 + b1[256 + L0], 0.f));
    Hb[(size_t)i * L1W + 256 + L1] = f2bf(fmaxf(a1 + b1[256 + L1], 0.f));
}

// ---------------- layer-2 prop over U8: 2 edge-groups x 32 cols -------------
// batch-of-4 per group + csr ping-pong prefetch + masked final batch

__global__ __launch_bounds__(256) void propU8_k(const unsigned char* __restrict__ U8,
                                                unsigned short* __restrict__ T2a,
                                                unsigned char* __restrict__ T8b,
                                                const int* __restrict__ rowptr,
                                                const unsigned int* __restrict__ csr,
                                                const float* __restrict__ dinv, int n) {
    int wave = threadIdx.x >> 6, lane = threadIdx.x & 63;
    int i = blockIdx.x * 4 + wave;
    if (i >= n) return;
    int beg = rowptr[i], end = rowptr[i + 1];
    float di = dinv[i];
    int g = lane >> 5, c = lane & 31;
    const unsigned int* sbase = (const unsigned int*)U8 + c;  // row stride 32 uints
    float a0 = 0.f, a1 = 0.f, a2 = 0.f, a3 = 0.f;
    if (g == 0) {
        unsigned int sv = sbase[(size_t)i * 32];
        float w = di * di;
        f32x2 lo = __builtin_amdgcn_cvt_pk_f32_fp8(sv, false);
        f32x2 hi = __builtin_amdgcn_cvt_pk_f32_fp8(sv, true);
        a0 = w * lo.x; a1 = w * lo.y; a2 = w * hi.x; a3 = w * hi.y;
    }

#define CONSU8(rr, vv)                                                        \
    _Pragma("unroll") for (int j = 0; j < 4; j++) {                           \
        float we = EDGE_W(rr[j]);                                             \
        f32x2 lo = __builtin_amdgcn_cvt_pk_f32_fp8(vv[j], false);             \
        f32x2 hi = __builtin_amdgcn_cvt_pk_f32_fp8(vv[j], true);              \
        a0 = fmaf(we, lo.x, a0);                                              \
        a1 = fmaf(we, lo.y, a1);                                              \
        a2 = fmaf(we, hi.x, a2);                                              \
        a3 = fmaf(we, hi.y, a3);                                              \
    }

    int k0 = beg + g;                                     // this group's first edge
    int cnt = (k0 < end) ? ((end - k0 + 1) >> 1) : 0;     // edges this group owns
    int nfull = cnt >> 2;
    unsigned int rrA[4], rrB[4];
    if (nfull > 0) {
#pragma unroll
        for (int j = 0; j < 4; j++) rrA[j] = csr[k0 + 2 * j];
        int it = 0;
        while (it + 2 <= nfull) {
            {
                unsigned int vv[4];
#pragma unroll
                for (int j = 0; j < 4; j++) vv[j] = sbase[(size_t)EDGE_S(rrA[j]) * 32];
#pragma unroll
                for (int j = 0; j < 4; j++) rrB[j] = csr[k0 + ((it + 1) << 3) + 2 * j];
                CONSU8(rrA, vv)
            }
            {
                unsigned int vv[4];
#pragma unroll
                for (int j = 0; j < 4; j++) vv[j] = sbase[(size_t)EDGE_S(rrB[j]) * 32];
                if (it + 2 < nfull) {
#pragma unroll
                    for (int j = 0; j < 4; j++) rrA[j] = csr[k0 + ((it + 2) << 3) + 2 * j];
                }
                CONSU8(rrB, vv)
            }
            it += 2;
        }
        if (it < nfull) {
            unsigned int vv[4];
#pragma unroll
            for (int j = 0; j < 4; j++) vv[j] = sbase[(size_t)EDGE_S(rrA[j]) * 32];
            CONSU8(rrA, vv)
        }
    }
    int t0 = nfull << 2;
    if (t0 < cnt) {
        unsigned int rrt[4], vv[4];
#pragma unroll
        for (int j = 0; j < 4; j++) {
            int t = t0 + j;
            rrt[j] = csr[t < cnt ? k0 + 2 * t : beg];
        }
#pragma unroll
        for (int j = 0; j < 4; j++) vv[j] = sbase[(size_t)EDGE_S(rrt[j]) * 32];
#pragma unroll
        for (int j = 0; j < 4; j++) {
            float we = (t0 + j < cnt) ? EDGE_W(rrt[j]) : 0.f;
            f32x2 lo = __builtin_amdgcn_cvt_pk_f32_fp8(vv[j], false);
            f32x2 hi = __builtin_amdgcn_cvt_pk_f32_fp8(vv[j], true);
            a0 = fmaf(we, lo.x, a0);
            a1 = fmaf(we, lo.y, a1);
            a2 = fmaf(we, hi.x, a2);
            a3 = fmaf(we, hi.y, a3);
        }
    }
#undef CONSU8
    a0 += __shfl_xor(a0, 32, 64);
    a1 += __shfl_xor(a1, 32, 64);
    a2 += __shfl_xor(a2, 32, 64);
    a3 += __shfl_xor(a3, 32, 64);
    if (lane < 32) {
        int m = lane >> 1, sb = 4 * (lane & 1);
        float av[4] = {a0, a1, a2, a3};
#pragma unroll
        for (int j = 0; j < 4; j++) {
            int L = (sb + j) * 16 + m;
            if (L >= 40 && L < 80) T2a[(size_t)i * 40 + (L - 40)] = f2bf(av[j]);
            else if (L >= 80 && L < 120) T8b[(size_t)i * 40 + (L - 80)] = pack_fp8x1(av[j]);
        }
    }
}

// ---------------- fused second-hop prop + log_softmax -----------------------
// 6 groups x 10 lanes, batch-of-4 per group + prefetch + masked final batch

__global__ __launch_bounds__(256) void lsm_prop_k(const unsigned short* __restrict__ Ub,
                                                  const unsigned short* __restrict__ T2a,
                                                  const unsigned char* __restrict__ T8b,
                                                  const int* __restrict__ rowptr,
                                                  const unsigned int* __restrict__ csr,
                                                  const float* __restrict__ dinv,
                                                  const float* __restrict__ b2,
                                                  float* __restrict__ out, int n) {
    int wave = threadIdx.x >> 6;
    int lane = threadIdx.x & 63;
    int i = blockIdx.x * 4 + wave;
    if (i >= n) return;
    int beg = rowptr[i], end = rowptr[i + 1];
    float di = dinv[i];
    int g = lane / 10;           // 0..6 (lanes 60..63 inactive)
    int c = lane - g * 10;       // 0..9
    bool act = lane < 60;
    const unsigned int* sb = (const unsigned int*)T8b + c;  // row stride 10 uints
    float a0 = 0.f, a1 = 0.f, a2 = 0.f, a3 = 0.f;
    if (lane < 10) {  // self term counted once (group 0)
        unsigned int sv = sb[(size_t)i * 10];
        float w = di * di;
        f32x2 lo = __builtin_amdgcn_cvt_pk_f32_fp8(sv, false);
        f32x2 hi = __builtin_amdgcn_cvt_pk_f32_fp8(sv, true);
        a0 = w * lo.x; a1 = w * lo.y; a2 = w * hi.x; a3 = w * hi.y;
    }

#define CONSLS(rr, vv)                                                        \
    _Pragma("unroll") for (int j = 0; j < 4; j++) {                           \
        float we = EDGE_W(rr[j]);                                             \
        f32x2 lo = __builtin_amdgcn_cvt_pk_f32_fp8(vv[j], false);             \
        f32x2 hi = __builtin_amdgcn_cvt_pk_f32_fp8(vv[j], true);              \
        a0 = fmaf(we, lo.x, a0);                                              \
        a1 = fmaf(we, lo.y, a1);                                              \
        a2 = fmaf(we, hi.x, a2);                                              \
        a3 = fmaf(we, hi.y, a3);                                              \
    }

    int k0 = beg + g;
    int cnt = (act && k0 < end) ? ((end - k0 + 5) / 6) : 0;  // edges this group owns
    int nfull = cnt >> 2;
    unsigned int rrA[4], rrB[4];
    if (nfull > 0) {
#pragma unroll
        for (int j = 0; j < 4; j++) rrA[j] = csr[k0 + 6 * j];
        int it = 0;
        while (it + 2 <= nfull) {
            {
                unsigned int vv[4];
#pragma unroll
                for (int j = 0; j < 4; j++) vv[j] = sb[(size_t)EDGE_S(rrA[j]) * 10];
#pragma unroll
                for (int j = 0; j < 4; j++) rrB[j] = csr[k0 + (it + 1) * 24 + 6 * j];
                CONSLS(rrA, vv)
            }
            {
                unsigned int vv[4];
#pragma unroll
                for (int j = 0; j < 4; j++) vv[j] = sb[(size_t)EDGE_S(rrB[j]) * 10];
                if (it + 2 < nfull) {
#pragma unroll
                    for (int j = 0; j < 4; j++) rrA[j] = csr[k0 + (it + 2) * 24 + 6 * j];
                }
                CONSLS(rrB, vv)
            }
            it += 2;
        }
        if (it < nfull) {
            unsigned int vv[4];
#pragma unroll
            for (int j = 0; j < 4; j++) vv[j] = sb[(size_t)EDGE_S(rrA[j]) * 10];
            CONSLS(rrA, vv)
        }
    }
    int t0 = nfull << 2;
    if (t0 < cnt) {
        unsigned int rrt[4], vv[4];
#pragma unroll
        for (int j = 0; j < 4; j++) {
            int t = t0 + j;
            rrt[j] = csr[t < cnt ? k0 + 6 * t : beg];
        }
#pragma unroll
        for (int j = 0; j < 4; j++) vv[j] = sb[(size_t)EDGE_S(rrt[j]) * 10];
#pragma unroll
        for (int j = 0; j < 4; j++) {
            float we = (t0 + j < cnt) ? EDGE_W(rrt[j]) : 0.f;
            f32x2 lo = __builtin_amdgcn_cvt_pk_f32_fp8(vv[j], false);
            f32x2 hi = __builtin_amdgcn_cvt_pk_f32_fp8(vv[j], true);
            a0 = fmaf(we, lo.x, a0);
            a1 = fmaf(we, lo.y, a1);
            a2 = fmaf(we, hi.x, a2);
            a3 = fmaf(we, hi.y, a3);
        }
    }
#undef CONSLS
    // reduce the 6 group partials into lanes 0..9 (results valid there only)
    float r0s = a0, r1s = a1, r2s = a2, r3s = a3;
#pragma unroll
    for (int g2 = 1; g2 < 6; g2++) {
        r0s += __shfl(a0, lane + 10 * g2, 64);
        r1s += __shfl(a1, lane + 10 * g2, 64);
        r2s += __shfl(a2, lane + 10 * g2, 64);
        r3s += __shfl(a3, lane + 10 * g2, 64);
    }
    // redistribute: lane j1=lane+64 needs col idx=j1-80 from lane idx>>2, comp idx&3
    int j1 = lane + 64;
    int idx = j1 - 80;
    int srcl = (idx < 0) ? 0 : (idx >> 2);
    float s0v = __shfl(r0s, srcl, 64);
    float s1v = __shfl(r1s, srcl, 64);
    float s2v = __shfl(r2s, srcl, 64);
    float s3v = __shfl(r3s, srcl, 64);
    int comp = idx & 3;
    float pv = (comp == 0) ? s0v : (comp == 1) ? s1v : (comp == 2) ? s2v : s3v;
    float v0, v1;
    {
        int j = lane;  // 0..63
        float v = (j >= 40) ? bf2f(T2a[(size_t)i * 40 + (j - 40)]) : bf2f(Ub[(size_t)i * L2WP + j]);
        v0 = v + b2[j];
    }
    if (j1 < 120) {
        float v = (j1 < 80) ? bf2f(T2a[(size_t)i * 40 + (j1 - 40)]) : pv;
        v1 = v + b2[j1];
    } else {
        v1 = -INFINITY;
    }
    float m = fmaxf(v0, v1);
    for (int off = 32; off; off >>= 1) m = fmaxf(m, __shfl_xor(m, off, 64));
    float s = expf(v0 - m) + ((j1 < 120) ? expf(v1 - m) : 0.f);
    for (int off = 32; off; off >>= 1) s += __shfl_xor(s, off, 64);
    float ls = logf(s) + m;
    out[(size_t)i * 120 + lane] = v0 - ls;
    if (j1 < 120) out[(size_t)i * 120 + j1] = v1 - ls;
}

// ---------------- launch ----------------

static inline size_t align256(size_t x) { return (x + 255) & ~(size_t)255; }

extern "C" void kernel_launch(void* const* d_in, const int* in_sizes, int n_in,
                              void* d_out, int out_size, void* d_ws, size_t ws_size,
                              hipStream_t stream) {
    const float* x = (const float*)d_in[0];
    const int* ei = (const int*)d_in[1];
    const float* W1_0 = (const float*)d_in[2];
    const float* W1_1 = (const float*)d_in[3];
    const float* W1_2 = (const float*)d_in[4];
    const float* b1 = (const float*)d_in[5];
    const float* W2_0 = (const float*)d_in[6];
    const float* W2_1 = (const float*)d_in[7];
    const float* W2_2 = (const float*)d_in[8];
    const float* b2 = (const float*)d_in[9];
    float* out = (float*)d_out;

    const int n = N_NODES;
    const int E = in_sizes[1] / 2;
    const int nb = (n + 255) / 256;
    const int nbe4 = ((E + 3) / 4 + 255) / 256;
    const int n2 = NBUK * NBLK1;
    const int nb2 = (n2 + 255) / 256;

    char* p = (char*)d_ws;
    size_t off = 0;
    auto alloc = [&](size_t bytes) {
        void* r = p + off;
        off = align256(off + bytes);
        return r;
    };
    int* flag = (int*)alloc(4);
    int* cnt = (int*)alloc((size_t)n * 4);
    int* rowptr = (int*)alloc((size_t)(n + 1) * 4);
    int* bsum = (int*)alloc((size_t)nb * 4);
    float* dinv = (float*)alloc((size_t)n * 4);
    unsigned int* csr = (unsigned int*)alloc((size_t)E * 4);
    int* cnt2 = (int*)alloc((size_t)n2 * 4);
    int* off2 = (int*)alloc((size_t)n2 * 4);
    int* bsum2 = (int*)alloc((size_t)nb2 * 4);
    int* tot2 = (int*)alloc(4);
    unsigned int* stage = (unsigned int*)alloc((size_t)E * 4);
    unsigned short* Bp1 = (unsigned short*)alloc((size_t)N1PACK * 2);
    unsigned short* Bp2 = (unsigned short*)alloc((size_t)N2PACK * 2);
    unsigned short* Hb = (unsigned short*)alloc((size_t)n * L1W * 2);
    unsigned char* Y8 = (unsigned char*)alloc((size_t)n * 256);
    unsigned char* T8 = (unsigned char*)alloc((size_t)n * 128);
    unsigned short* Ub = (unsigned short*)alloc((size_t)n * L2WP * 2);
    unsigned char* U8 = (unsigned char*)alloc((size_t)n * 128);
    unsigned short* T2a = (unsigned short*)alloc((size_t)n * C_OUT * 2);
    unsigned char* T8b = (unsigned char*)alloc((size_t)n * C_OUT);
    (void)ws_size;

    // 0. edge dtype detect
    detect_k<<<1, 256, 0, stream>>>(ei, flag);

    // 1. per-node degree + rowptr (+dinv fused)
    hipMemsetAsync(cnt, 0, (size_t)n * 4, stream);
    hist_k<<<nbe4, 256, 0, stream>>>(ei, flag, cnt, E);
    scan1_k<<<nb, 256, 0, stream>>>(cnt, bsum, n);
    scan2_k<<<1, 256, 0, stream>>>(bsum, rowptr + n, nb);
    scan3_k<<<nb, 256, 0, stream>>>(cnt, bsum, rowptr, dinv, n);

    // 2. two-phase binned scatter -> csr
    hist2_k<<<NBLK1, 256, 0, stream>>>(ei, flag, cnt2, E);
    scan1_k<<<nb2, 256, 0, stream>>>(cnt2, bsum2, n2);
    scan2_k<<<1, 256, 0, stream>>>(bsum2, tot2, nb2);
    scan3_k<<<nb2, 256, 0, stream>>>(cnt2, bsum2, off2, (float*)nullptr, n2);
    stage_k<<<NBLK1, 256, 0, stream>>>(ei, flag, off2, stage, E);
    scatter2_k<<<NBUK, 256, 0, stream>>>(stage, off2, rowptr, dinv, csr, E, n);

    // 3. weight packing (merged)
    pack_k<<<(N1PACK + N2PACK + 255) / 256, 256, 0, stream>>>(W1_0, W1_1, W1_2,
                                                              W2_0, W2_1, W2_2, Bp1, Bp2);

    // 4. layer 1 GEMM (z1 -> Hb bf16, y2 -> Y8 fp8 transposed)
    mgemm1_k<<<(n + 63) / 64, 256, 0, stream>>>(x, Bp1, b1, Hb, Y8, n);
    prop256f_k<<<(n + 3) / 4, 256, 0, stream>>>(Y8, Hb, T8, rowptr, csr, dinv, b1, n);
    prop128f_k<<<(n + 3) / 4, 256, 0, stream>>>(T8, Hb, rowptr, csr, dinv, b1, n);

    // 5. layer 2 GEMM -> Ub bf16 (cols<48) + U8 fp8 (1 line/row)
    mgemm2_k<<<(n + 63) / 64, 256, 0, stream>>>(Hb, Bp2, Ub, U8, n);
    propU8_k<<<(n + 3) / 4, 256, 0, stream>>>(U8, T2a, T8b, rowptr, csr, dinv, n);

    // 6. fused second hop + log_softmax
    lsm_prop_k<<<(n + 3) / 4, 256, 0, stream>>>(Ub, T2a, T8b, rowptr, csr, dinv, b2, out, n);
}

// Round 7
// 327.213 us; speedup vs baseline: 1.1905x; 1.0516x over previous
//
#include <hip/hip_runtime.h>
#include <hip/hip_bf16.h>
#include <math.h>

#define N_NODES 50000
#define F_IN 256
#define H1 128
#define C_OUT 40
#define L1W 384   // 3*H1
#define L2W 120   // 3*C_OUT
#define L2WP 128  // padded
#define NBUK 196  // ceil(50000/256) dst buckets of 256 nodes
#define NBLK1 256 // phase-1 blocks

typedef __attribute__((ext_vector_type(8))) short short8;
typedef __attribute__((ext_vector_type(4))) float f32x4;
typedef __attribute__((ext_vector_type(2))) float f32x2;

typedef __attribute__((address_space(1))) const unsigned int gu32;
typedef __attribute__((address_space(3))) unsigned int lu32;

__device__ __forceinline__ void g2l16(const void* g, void* l) {
    __builtin_amdgcn_global_load_lds((gu32*)g, (lu32*)l, 16, 0, 0);
}

__device__ inline unsigned short f2bf(float f) {
    union { float f; unsigned int u; } x;
    x.f = f;
    unsigned int u = x.u;
    return (unsigned short)((u + 0x7FFF + ((u >> 16) & 1)) >> 16);
}
__device__ inline float bf2f(unsigned short u) {
    union { unsigned int u; float f; } x;
    x.u = (unsigned int)u << 16;
    return x.f;
}
__device__ inline unsigned int pack_fp8x4(float a, float b, float c, float d) {
    int v = 0;
    v = __builtin_amdgcn_cvt_pk_fp8_f32(a, b, v, false);  // bytes 0,1
    v = __builtin_amdgcn_cvt_pk_fp8_f32(c, d, v, true);   // bytes 2,3
    return (unsigned int)v;
}
__device__ inline unsigned short pack_fp8x2(float a, float b) {
    return (unsigned short)(__builtin_amdgcn_cvt_pk_fp8_f32(a, b, 0, false) & 0xFFFF);
}
__device__ inline unsigned char pack_fp8x1(float a) {
    return (unsigned char)(__builtin_amdgcn_cvt_pk_fp8_f32(a, a, 0, false) & 0xFF);
}
// decode 4B edge record {w:bf16:16 | src:16}
#define EDGE_S(r) ((int)((r) & 0xFFFFu))
#define EDGE_W(r) bf2f((unsigned short)((r) >> 16))

// ---------------- inline edge-index dtype detection (per-wave, no launch) ----
// int64 layout: odd int32 words are hi-halves of node ids < 2^31 -> all 0.
// int32 layout: odd words are src values, ~never all zero over 256 samples.

__device__ __forceinline__ bool detect_i32(const int* __restrict__ ei) {
    int lane = threadIdx.x & 63;
    int v = ei[2 * lane + 1] | ei[2 * (lane + 64) + 1] |
            ei[2 * (lane + 128) + 1] | ei[2 * (lane + 192) + 1];
    return __ballot(v != 0) != 0ULL;
}

// ---------------- fused: per-node hist + bucket hist + weight pack ----------
// blocks [0, NBLK1): edge chunk -> atomicAdd cnt[dst] + LDS bucket hist -> cnt2
// blocks [NBLK1, NBLK1+PACKB): weight packing (independent work, free ride)
// Pack tile-internal layout: off = kq*128 + m*8 + kk (G2L lane-linear).

#define N1PACK ((F_IN / 32) * L1W * 32)
#define N2PACK ((L1W / 32) * L2WP * 32)
#define PACKB ((N1PACK + N2PACK + 255) / 256)

__global__ __launch_bounds__(256) void fhist_k(const int* __restrict__ ei,
                                               const float* __restrict__ w10,
                                               const float* __restrict__ w11,
                                               const float* __restrict__ w12,
                                               const float* __restrict__ w20,
                                               const float* __restrict__ w21,
                                               const float* __restrict__ w22,
                                               int* __restrict__ cnt,
                                               int* __restrict__ cnt2,
                                               unsigned short* __restrict__ Bp1,
                                               unsigned short* __restrict__ Bp2, int E) {
    __shared__ int lcnt[NBUK];
    int t = threadIdx.x, blk = blockIdx.x;
    if (blk < NBLK1) {
        bool i32 = detect_i32(ei);
        for (int j = t; j < NBUK; j += 256) lcnt[j] = 0;
        __syncthreads();
        int chunk = (E + NBLK1 - 1) / NBLK1;
        int beg = blk * chunk, end = min(beg + chunk, E);
        const long long* e64 = (const long long*)ei;
        for (int e = beg + t; e < end; e += 256) {
            int d = i32 ? ei[E + e] : (int)e64[E + e];
            atomicAdd(&cnt[d], 1);
            atomicAdd(&lcnt[d >> 8], 1);
        }
        __syncthreads();
        for (int j = t; j < NBUK; j += 256) cnt2[j * NBLK1 + blk] = lcnt[j];  // bucket-major
    } else {
        int idx = (blk - NBLK1) * 256 + t;
        if (idx < N1PACK) {
            int kt = idx / (L1W * 32);
            int tt = idx % (L1W * 32);
            int s = tt >> 9;
            int u = tt & 511;
            int kq = u >> 7, m = (u >> 3) & 15, kk = u & 7;
            int col = s * 16 + m;
            int k = kt * 32 + kq * 8 + kk;
            int p = col >> 7, c = col & 127;
            const float* w = (p == 0) ? w10 : (p == 1) ? w11 : w12;
            Bp1[idx] = f2bf(w[k * H1 + c]);
        } else if (idx < N1PACK + N2PACK) {
            int j = idx - N1PACK;
            int kt = j / (L2WP * 32);
            int tt = j % (L2WP * 32);
            int s = tt >> 9;
            int u = tt & 511;
            int kq = u >> 7, m = (u >> 3) & 15, kk = u & 7;
            int col = s * 16 + m;
            int k = kt * 32 + kq * 8 + kk;
            unsigned short v = 0;
            if (col < L2W) {
                int p = col / 40, c = col % 40;
                const float* w = (p == 0) ? w20 : (p == 1) ? w21 : w22;
                v = f2bf(w[k * C_OUT + c]);
            }
            Bp2[j] = v;
        }
    }
}

// ---------------- fused 3-level exclusive scans (node chain + bucket chain) --

__global__ __launch_bounds__(256) void fscan1_k(const int* __restrict__ cntA,
                                                int* __restrict__ bsumA, int nA,
                                                const int* __restrict__ cntB,
                                                int* __restrict__ bsumB, int nB, int nbA) {
    int b = blockIdx.x;
    const int* cnt;
    int* bsum;
    int n, bb;
    if (b < nbA) { cnt = cntA; bsum = bsumA; n = nA; bb = b; }
    else         { cnt = cntB; bsum = bsumB; n = nB; bb = b - nbA; }
    int t = threadIdx.x;
    int i = bb * 256 + t;
    int v = (i < n) ? cnt[i] : 0;
    for (int off = 32; off; off >>= 1) v += __shfl_down(v, off, 64);
    __shared__ int ws[4];
    if ((t & 63) == 0) ws[t >> 6] = v;
    __syncthreads();
    if (t == 0) bsum[bb] = ws[0] + ws[1] + ws[2] + ws[3];
}

__global__ __launch_bounds__(256) void fscan2_k(int* __restrict__ bsumA,
                                                int* __restrict__ btotA, int nbA,
                                                int* __restrict__ bsumB,
                                                int* __restrict__ btotB, int nbB) {
    int* bsum;
    int* btot;
    int nb;
    if (blockIdx.x == 0) { bsum = bsumA; btot = btotA; nb = nbA; }
    else                 { bsum = bsumB; btot = btotB; nb = nbB; }
    __shared__ int s[256];
    int t = threadIdx.x;
    int v = (t < nb) ? bsum[t] : 0;
    s[t] = v;
    __syncthreads();
    for (int off = 1; off < 256; off <<= 1) {
        int u = (t >= off) ? s[t - off] : 0;
        __syncthreads();
        s[t] += u;
        __syncthreads();
    }
    if (t < nb) bsum[t] = s[t] - v;  // exclusive
    if (t == nb - 1) *btot = s[t];
}

__global__ __launch_bounds__(256) void fscan3_k(const int* __restrict__ cntA,
                                                const int* __restrict__ bsumA,
                                                int* __restrict__ rpA,
                                                float* __restrict__ dinv, int nA,
                                                const int* __restrict__ cntB,
                                                const int* __restrict__ bsumB,
                                                int* __restrict__ rpB, int nB, int nbA) {
    int b = blockIdx.x;
    const int* cnt;
    const int* bsum;
    int* rowptr;
    float* dv;
    int n, bb;
    if (b < nbA) { cnt = cntA; bsum = bsumA; rowptr = rpA; dv = dinv; n = nA; bb = b; }
    else         { cnt = cntB; bsum = bsumB; rowptr = rpB; dv = nullptr; n = nB; bb = b - nbA; }
    __shared__ int s[256];
    int t = threadIdx.x;
    int i = bb * 256 + t;
    int v = (i < n) ? cnt[i] : 0;
    s[t] = v;
    __syncthreads();
    for (int off = 1; off < 256; off <<= 1) {
        int u = (t >= off) ? s[t - off] : 0;
        __syncthreads();
        s[t] += u;
        __syncthreads();
    }
    if (i < n) {
        rowptr[i] = s[t] - v + bsum[bb];
        if (dv) dv[i] = rsqrtf((float)v + 1.0f);
    }
}

// ---------------- two-phase binned scatter ----------------------------------

__global__ __launch_bounds__(256) void stage_k(const int* __restrict__ ei,
                                               const int* __restrict__ off2,
                                               unsigned int* __restrict__ stage, int E) {
    __shared__ int lcur[NBUK];
    bool i32 = detect_i32(ei);
    int t = threadIdx.x, blk = blockIdx.x;
    for (int j = t; j < NBUK; j += 256) lcur[j] = off2[j * NBLK1 + blk];
    __syncthreads();
    int chunk = (E + NBLK1 - 1) / NBLK1;
    int beg = blk * chunk, end = min(beg + chunk, E);
    const long long* e64 = (const long long*)ei;
    for (int e = beg + t; e < end; e += 256) {
        int s, d;
        if (i32) { s = ei[e]; d = ei[E + e]; }
        else { s = (int)e64[e]; d = (int)e64[E + e]; }
        int b = d >> 8;
        int pos = atomicAdd(&lcur[b], 1);
        stage[pos] = ((unsigned int)(d & 255) << 16) | (unsigned int)s;
    }
}

__global__ __launch_bounds__(256) void scatter2_k(const unsigned int* __restrict__ stage,
                                                  const int* __restrict__ off2,
                                                  const int* __restrict__ rowptr,
                                                  const float* __restrict__ dinv,
                                                  unsigned int* __restrict__ csr,
                                                  int E, int n) {
    __shared__ int lfill[256];
    int b = blockIdx.x, t = threadIdx.x;
    int node0 = b << 8;
    int node = node0 + t;
    lfill[t] = (node < n) ? rowptr[node] : 0;
    __syncthreads();
    int segBeg = off2[b * NBLK1];
    int segEnd = (b == NBUK - 1) ? E : off2[(b + 1) * NBLK1];
    for (int e = segBeg + t; e < segEnd; e += 256) {
        unsigned int rec = stage[e];
        int dl = rec >> 16;
        int s = rec & 0xFFFF;
        int d = node0 + dl;
        float w = dinv[s] * dinv[d];
        int pos = atomicAdd(&lfill[dl], 1);
        csr[pos] = ((unsigned int)f2bf(w) << 16) | (unsigned int)s;
    }
}

// ---------------- layer-1 GEMM: counted-vmcnt pipeline, raw barriers --------
// Block = 64 rows x 384 cols, 4 waves; wave = 16 rows (full-K A preload) x all
// 24 N-tiles. B staged per block via G2L into shared 2-slot LDS. Per kt:
// counted vmcnt (prefetch stays in flight) -> barrier -> compiler-scheduled
// ds_read+MFMA (setprio around cluster) -> lgkmcnt(0) -> barrier -> refill.

__global__ __launch_bounds__(256, 2) void mgemm1_k(const float* __restrict__ A,
                                                   const unsigned short* __restrict__ Bp,
                                                   const float* __restrict__ b1,
                                                   unsigned short* __restrict__ Hb,
                                                   unsigned char* __restrict__ Y8, int N) {
    __shared__ unsigned short Bls[2][L1W * 32];  // 2 slots x 24 KB
    int tid = threadIdx.x;
    int w = tid >> 6, lane = tid & 63;
    int m = lane & 15, kq = lane >> 4;
    int row0 = blockIdx.x * 64 + w * 16;
    int arow = row0 + m;
    if (arow >= N) arow = N - 1;  // clamped duplicate; stores guarded
    const float* Ap = A + (size_t)arow * F_IN + kq * 8;
    const char* srcb = (const char*)Bp + (size_t)(w * 6) * 1024 + (size_t)lane * 16;

    // 1) issue ALL A loads first (16 dwordx4 in flight)
    float4 at0[8], at1[8];
#pragma unroll
    for (int kt = 0; kt < 8; kt++) {
        at0[kt] = *(const float4*)(Ap + kt * 32);
        at1[kt] = *(const float4*)(Ap + kt * 32 + 4);
    }
    // 2) issue G2L for slots 0 and 1 (wave w: tiles 6w..6w+5)
#pragma unroll
    for (int j = 0; j < 6; j++) g2l16(srcb + j * 1024, &Bls[0][(w * 6 + j) * 512]);
#pragma unroll
    for (int j = 0; j < 6; j++) g2l16(srcb + 24576 + j * 1024, &Bls[1][(w * 6 + j) * 512]);
    // 3) convert A -> bf16 (compiler waits the A loads; G2L stay outstanding)
    short8 areg[8];
#pragma unroll
    for (int kt = 0; kt < 8; kt++) {
        float4 u = at0[kt], v = at1[kt];
        short8 a;
        a[0] = (short)f2bf(u.x); a[1] = (short)f2bf(u.y);
        a[2] = (short)f2bf(u.z); a[3] = (short)f2bf(u.w);
        a[4] = (short)f2bf(v.x); a[5] = (short)f2bf(v.y);
        a[6] = (short)f2bf(v.z); a[7] = (short)f2bf(v.w);
        areg[kt] = a;
    }

    f32x4 acc[24];
#pragma unroll
    for (int s = 0; s < 24; s++) acc[s] = (f32x4){0.f, 0.f, 0.f, 0.f};

#pragma unroll
    for (int kt = 0; kt < 8; kt++) {
        // my 6 tiles of slot kt landed (G2L(kt+1) still in flight)
        if (kt < 7) { asm volatile("s_waitcnt vmcnt(6)" ::: "memory"); }
        else        { asm volatile("s_waitcnt vmcnt(0)" ::: "memory"); }
        __builtin_amdgcn_s_barrier();  // all waves' tiles for slot kt landed
        __builtin_amdgcn_sched_barrier(0);
        const unsigned short* Bbuf = Bls[kt & 1];
        __builtin_amdgcn_s_setprio(1);
#pragma unroll
        for (int c = 0; c < 4; c++) {
            short8 bf[6];
#pragma unroll
            for (int j = 0; j < 6; j++)
                bf[j] = *(const short8*)(&Bbuf[(c * 6 + j) * 512 + lane * 8]);
#pragma unroll
            for (int j = 0; j < 6; j++)
                acc[c * 6 + j] = __builtin_amdgcn_mfma_f32_16x16x32_bf16(
                    areg[kt], bf[j], acc[c * 6 + j], 0, 0, 0);
        }
        __builtin_amdgcn_s_setprio(0);
        asm volatile("s_waitcnt lgkmcnt(0)" ::: "memory");  // reads retired
        __builtin_amdgcn_s_barrier();                       // slot kt reusable
        if (kt < 6) {
#pragma unroll
            for (int j = 0; j < 6; j++)
                g2l16(srcb + (size_t)(kt + 2) * 24576 + j * 1024,
                      &Bls[kt & 1][(w * 6 + j) * 512]);
        }
    }

    int crow = row0 + kq * 4;
#pragma unroll
    for (int s = 0; s < 8; s++) {
        int col = s * 16 + m;
        float bias = b1[col];
#pragma unroll
        for (int r2 = 0; r2 < 4; r2++) {
            int row = crow + r2;
            if (row < N) Hb[(size_t)row * L1W + col] = f2bf(fmaxf(acc[s][r2] + bias, 0.f));
        }
    }
#pragma unroll
    for (int r2 = 0; r2 < 4; r2++) {
        int row = crow + r2;
        if (row < N) {
            uint4 u;
            u.x = pack_fp8x4(acc[8][r2], acc[9][r2], acc[10][r2], acc[11][r2]);
            u.y = pack_fp8x4(acc[12][r2], acc[13][r2], acc[14][r2], acc[15][r2]);
            u.z = pack_fp8x4(acc[16][r2], acc[17][r2], acc[18][r2], acc[19][r2]);
            u.w = pack_fp8x4(acc[20][r2], acc[21][r2], acc[22][r2], acc[23][r2]);
            *(uint4*)(Y8 + (size_t)row * 256 + m * 16) = u;
        }
    }
}

// ---------------- layer-2 GEMM: same counted-vmcnt structure ----------------

__global__ __launch_bounds__(256, 3) void mgemm2_k(const unsigned short* __restrict__ A,
                                                   const unsigned short* __restrict__ Bp,
                                                   unsigned short* __restrict__ Ub,
                                                   unsigned char* __restrict__ U8, int N) {
    __shared__ unsigned short Bls[2][L2WP * 32];  // 2 slots x 8 KB
    int tid = threadIdx.x;
    int w = tid >> 6, lane = tid & 63;
    int m = lane & 15, kq = lane >> 4;
    int row0 = blockIdx.x * 64 + w * 16;
    int arow = row0 + m;
    if (arow >= N) arow = N - 1;
    const unsigned short* Ap = A + (size_t)arow * L1W + kq * 8;
    const char* srcb = (const char*)Bp + (size_t)(w * 2) * 1024 + (size_t)lane * 16;

    short8 areg[12];
#pragma unroll
    for (int kt = 0; kt < 12; kt++) areg[kt] = *(const short8*)(Ap + kt * 32);
#pragma unroll
    for (int j = 0; j < 2; j++) g2l16(srcb + j * 1024, &Bls[0][(w * 2 + j) * 512]);
#pragma unroll
    for (int j = 0; j < 2; j++) g2l16(srcb + 8192 + j * 1024, &Bls[1][(w * 2 + j) * 512]);

    f32x4 acc[8];
#pragma unroll
    for (int s = 0; s < 8; s++) acc[s] = (f32x4){0.f, 0.f, 0.f, 0.f};

#pragma unroll
    for (int kt = 0; kt < 12; kt++) {
        if (kt < 11) { asm volatile("s_waitcnt vmcnt(2)" ::: "memory"); }
        else         { asm volatile("s_waitcnt vmcnt(0)" ::: "memory"); }
        __builtin_amdgcn_s_barrier();
        __builtin_amdgcn_sched_barrier(0);
        const unsigned short* Bbuf = Bls[kt & 1];
        __builtin_amdgcn_s_setprio(1);
        short8 bf[8];
#pragma unroll
        for (int j = 0; j < 8; j++)
            bf[j] = *(const short8*)(&Bbuf[j * 512 + lane * 8]);
#pragma unroll
        for (int j = 0; j < 8; j++)
            acc[j] = __builtin_amdgcn_mfma_f32_16x16x32_bf16(areg[kt], bf[j], acc[j], 0, 0, 0);
        __builtin_amdgcn_s_setprio(0);
        asm volatile("s_waitcnt lgkmcnt(0)" ::: "memory");
        __builtin_amdgcn_s_barrier();
        if (kt < 10) {
#pragma unroll
            for (int j = 0; j < 2; j++)
                g2l16(srcb + (size_t)(kt + 2) * 8192 + j * 1024,
                      &Bls[kt & 1][(w * 2 + j) * 512]);
        }
    }

    int crow = row0 + kq * 4;
#pragma unroll
    for (int s = 0; s < 3; s++) {
        int col = s * 16 + m;
#pragma unroll
        for (int r2 = 0; r2 < 4; r2++) {
            int row = crow + r2;
            if (row < N) Ub[(size_t)row * L2WP + col] = f2bf(acc[s][r2]);
        }
    }
#pragma unroll
    for (int r2 = 0; r2 < 4; r2++) {
        int row = crow + r2;
        if (row < N) {
            uint2 u;
            u.x = pack_fp8x4(acc[0][r2], acc[1][r2], acc[2][r2], acc[3][r2]);
            u.y = pack_fp8x4(acc[4][r2], acc[5][r2], acc[6][r2], acc[7][r2]);
            *(uint2*)(U8 + (size_t)row * 128 + m * 8) = u;
        }
    }
}

// ---------------- fused width-256 fp8 prop over Y8 --------------------------
// pipelined: ping-pong csr prefetch (rrA/rrB) + masked final batch (no serial tail)

__global__ __launch_bounds__(256) void prop256f_k(const unsigned char* __restrict__ Y8,
                                                  unsigned short* __restrict__ Hb,
                                                  unsigned char* __restrict__ T8,
                                                  const int* __restrict__ rowptr,
                                                  const unsigned int* __restrict__ csr,
                                                  const float* __restrict__ dinv,
                                                  const float* __restrict__ b1, int n) {
    int wave = threadIdx.x >> 6, lane = threadIdx.x & 63;
    int i = blockIdx.x * 4 + wave;
    if (i >= n) return;
    int beg = rowptr[i], end = rowptr[i + 1];
    float di = dinv[i];
    const unsigned int* sbase = (const unsigned int*)Y8 + lane;  // row stride 64 uints
    unsigned int sv = sbase[(size_t)i * 64];
    float w = di * di;
    f32x2 slo = __builtin_amdgcn_cvt_pk_f32_fp8(sv, false);
    f32x2 shi = __builtin_amdgcn_cvt_pk_f32_fp8(sv, true);
    float a0 = w * slo.x, a1 = w * slo.y, a2 = w * shi.x, a3 = w * shi.y;

#define CONS256(rr, vv)                                                       \
    _Pragma("unroll") for (int e = 0; e < 8; e++) {                           \
        float we = EDGE_W(rr[e]);                                             \
        f32x2 lo = __builtin_amdgcn_cvt_pk_f32_fp8(vv[e], false);             \
        f32x2 hi = __builtin_amdgcn_cvt_pk_f32_fp8(vv[e], true);              \
        a0 = fmaf(we, lo.x, a0);                                              \
        a1 = fmaf(we, lo.y, a1);                                              \
        a2 = fmaf(we, hi.x, a2);                                              \
        a3 = fmaf(we, hi.y, a3);                                              \
    }

    int nfull = (end - beg) >> 3;
    unsigned int rrA[8], rrB[8];
    if (nfull > 0) {
#pragma unroll
        for (int e = 0; e < 8; e++) rrA[e] = csr[beg + e];
        int it = 0;
        while (it + 2 <= nfull) {
            {
                unsigned int vv[8];
#pragma unroll
                for (int e = 0; e < 8; e++) vv[e] = sbase[(size_t)EDGE_S(rrA[e]) * 64];
#pragma unroll
                for (int e = 0; e < 8; e++) rrB[e] = csr[beg + ((it + 1) << 3) + e];
                CONS256(rrA, vv)
            }
            {
                unsigned int vv[8];
#pragma unroll
                for (int e = 0; e < 8; e++) vv[e] = sbase[(size_t)EDGE_S(rrB[e]) * 64];
                if (it + 2 < nfull) {
#pragma unroll
                    for (int e = 0; e < 8; e++) rrA[e] = csr[beg + ((it + 2) << 3) + e];
                }
                CONS256(rrB, vv)
            }
            it += 2;
        }
        if (it < nfull) {  // odd last full batch (in rrA)
            unsigned int vv[8];
#pragma unroll
            for (int e = 0; e < 8; e++) vv[e] = sbase[(size_t)EDGE_S(rrA[e]) * 64];
            CONS256(rrA, vv)
        }
    }
    int k = beg + (nfull << 3);
    if (k < end) {  // masked final batch: parallel loads, zeroed weights OOB
        unsigned int rrt[8];
#pragma unroll
        for (int e = 0; e < 8; e++) {
            int idx = k + e;
            rrt[e] = csr[idx < end ? idx : beg];
        }
        unsigned int vv[8];
#pragma unroll
        for (int e = 0; e < 8; e++) vv[e] = sbase[(size_t)EDGE_S(rrt[e]) * 64];
#pragma unroll
        for (int e = 0; e < 8; e++) {
            float we = (k + e < end) ? EDGE_W(rrt[e]) : 0.f;
            f32x2 lo = __builtin_amdgcn_cvt_pk_f32_fp8(vv[e], false);
            f32x2 hi = __builtin_amdgcn_cvt_pk_f32_fp8(vv[e], true);
            a0 = fmaf(we, lo.x, a0);
            a1 = fmaf(we, lo.y, a1);
            a2 = fmaf(we, hi.x, a2);
            a3 = fmaf(we, hi.y, a3);
        }
    }
#undef CONS256
    int m = lane >> 2, jj = lane & 3;
    if (jj < 2) {  // z1: logical cols L_j = (4*jj+j)*16 + m
        float av[4] = {a0, a1, a2, a3};
#pragma unroll
        for (int j = 0; j < 4; j++) {
            int L = (4 * jj + j) * 16 + m;
            Hb[(size_t)i * L1W + 128 + L] = f2bf(fmaxf(av[j] + b1[128 + L], 0.f));
        }
    } else {       // t2 -> T8 phys = m*8 + 4*(jj-2)
        unsigned int o = pack_fp8x4(a0, a1, a2, a3);
        *(unsigned int*)(T8 + (size_t)i * 128 + m * 8 + 4 * (jj - 2)) = o;
    }
}

// ---------------- width-128 fp8 prop: Hb[:,256:384] = relu(P(T8)+b1) --------

__global__ __launch_bounds__(256) void prop128f_k(const unsigned char* __restrict__ T8,
                                                  unsigned short* __restrict__ Hb,
                                                  const int* __restrict__ rowptr,
                                                  const unsigned int* __restrict__ csr,
                                                  const float* __restrict__ dinv,
                                                  const float* __restrict__ b1, int n) {
    int wave = threadIdx.x >> 6, lane = threadIdx.x & 63;
    int i = blockIdx.x * 4 + wave;
    if (i >= n) return;
    int beg = rowptr[i], end = rowptr[i + 1];
    float di = dinv[i];
    const unsigned short* sbase = (const unsigned short*)T8 + lane;  // row stride 64
    unsigned int sv = sbase[(size_t)i * 64];
    float w = di * di;
    f32x2 sd = __builtin_amdgcn_cvt_pk_f32_fp8(sv, false);
    float a0 = w * sd.x, a1 = w * sd.y;

#define CONS128(rr, vv)                                                       \
    _Pragma("unroll") for (int e = 0; e < 8; e++) {                           \
        float we = EDGE_W(rr[e]);                                             \
        f32x2 d = __builtin_amdgcn_cvt_pk_f32_fp8(vv[e], false);              \
        a0 = fmaf(we, d.x, a0);                                               \
        a1 = fmaf(we, d.y, a1);                                               \
    }

    int nfull = (end - beg) >> 3;
    unsigned int rrA[8], rrB[8];
    if (nfull > 0) {
#pragma unroll
        for (int e = 0; e < 8; e++) rrA[e] = csr[beg + e];
        int it = 0;
        while (it + 2 <= nfull) {
            {
                unsigned int vv[8];
#pragma unroll
                for (int e = 0; e < 8; e++) vv[e] = sbase[(size_t)EDGE_S(rrA[e]) * 64];
#pragma unroll
                for (int e = 0; e < 8; e++) rrB[e] = csr[beg + ((it + 1) << 3) + e];
                CONS128(rrA, vv)
            }
            {
                unsigned int vv[8];
#pragma unroll
                for (int e = 0; e < 8; e++) vv[e] = sbase[(size_t)EDGE_S(rrB[e]) * 64];
                if (it + 2 < nfull) {
#pragma unroll
                    for (int e = 0; e < 8; e++) rrA[e] = csr[beg + ((it + 2) << 3) + e];
                }
                CONS128(rrB, vv)
            }
            it += 2;
        }
        if (it < nfull) {
            unsigned int vv[8];
#pragma unroll
            for (int e = 0; e < 8; e++) vv[e] = sbase[(size_t)EDGE_S(rrA[e]) * 64];
            CONS128(rrA, vv)
        }
    }
    int k = beg + (nfull << 3);
    if (k < end) {
        unsigned int rrt[8];
#pragma unroll
        for (int e = 0; e < 8; e++) {
            int idx = k + e;
            rrt[e] = csr[idx < end ? idx : beg];
        }
        unsigned int vv[8];
#pragma unroll
        for (int e = 0; e < 8; e++) vv[e] = sbase[(size_t)EDGE_S(rrt[e]) * 64];
#pragma unroll
        for (int e = 0; e < 8; e++) {
            float we = (k + e < end) ? EDGE_W(rrt[e]) : 0.f;
            f32x2 d = __builtin_amdgcn_cvt_pk_f32_fp8(vv[e], false);
            a0 = fmaf(we, d.x, a0);
            a1 = fmaf(we, d.y, a1);
        }
    }
#undef CONS128
    int m = lane >> 2, u0 = (2 * lane) & 7;
    int L0 = u0 * 16 + m, L1 = (u0 + 1) * 16 + m;
    Hb[(size_t)i * L1W + 256 + L0] = f2bf(fmaxf(a0 + b1[256 + L0], 0.f));
    Hb[(size_t)i * L1W + 256 + L1] = f2bf(fmaxf(a1 + b1[256 + L1], 0.f));
}

// ---------------- layer-2 prop over U8: 2 edge-groups x 32 cols -------------
// batch-of-4 per group + csr ping-pong prefetch + masked final batch

__global__ __launch_bounds__(256) void propU8_k(const unsigned char* __restrict__ U8,
                                                unsigned short* __restrict__ T2a,
                                                unsigned char* __restrict__ T8b,
                                                const int* __restrict__ rowptr,
                                                const unsigned int* __restrict__ csr,
                                                const float* __restrict__ dinv, int n) {
    int wave = threadIdx.x >> 6, lane = threadIdx.x & 63;
    int i = blockIdx.x * 4 + wave;
    if (i >= n) return;
    int beg = rowptr[i], end = rowptr[i + 1];
    float di = dinv[i];
    int g = lane >> 5, c = lane & 31;
    const unsigned int* sbase = (const unsigned int*)U8 + c;  // row stride 32 uints
    float a0 = 0.f, a1 = 0.f, a2 = 0.f, a3 = 0.f;
    if (g == 0) {
        unsigned int sv = sbase[(size_t)i * 32];
        float w = di * di;
        f32x2 lo = __builtin_amdgcn_cvt_pk_f32_fp8(sv, false);
        f32x2 hi = __builtin_amdgcn_cvt_pk_f32_fp8(sv, true);
        a0 = w * lo.x; a1 = w * lo.y; a2 = w * hi.x; a3 = w * hi.y;
    }

#define CONSU8(rr, vv)                                                        \
    _Pragma("unroll") for (int j = 0; j < 4; j++) {                           \
        float we = EDGE_W(rr[j]);                                             \
        f32x2 lo = __builtin_amdgcn_cvt_pk_f32_fp8(vv[j], false);             \
        f32x2 hi = __builtin_amdgcn_cvt_pk_f32_fp8(vv[j], true);              \
        a0 = fmaf(we, lo.x, a0);                                              \
        a1 = fmaf(we, lo.y, a1);                                              \
        a2 = fmaf(we, hi.x, a2);                                              \
        a3 = fmaf(we, hi.y, a3);                                              \
    }

    int k0 = beg + g;                                     // this group's first edge
    int cnt = (k0 < end) ? ((end - k0 + 1) >> 1) : 0;     // edges this group owns
    int nfull = cnt >> 2;
    unsigned int rrA[4], rrB[4];
    if (nfull > 0) {
#pragma unroll
        for (int j = 0; j < 4; j++) rrA[j] = csr[k0 + 2 * j];
        int it = 0;
        while (it + 2 <= nfull) {
            {
                unsigned int vv[4];
#pragma unroll
                for (int j = 0; j < 4; j++) vv[j] = sbase[(size_t)EDGE_S(rrA[j]) * 32];
#pragma unroll
                for (int j = 0; j < 4; j++) rrB[j] = csr[k0 + ((it + 1) << 3) + 2 * j];
                CONSU8(rrA, vv)
            }
            {
                unsigned int vv[4];
#pragma unroll
                for (int j = 0; j < 4; j++) vv[j] = sbase[(size_t)EDGE_S(rrB[j]) * 32];
                if (it + 2 < nfull) {
#pragma unroll
                    for (int j = 0; j < 4; j++) rrA[j] = csr[k0 + ((it + 2) << 3) + 2 * j];
                }
                CONSU8(rrB, vv)
            }
            it += 2;
        }
        if (it < nfull) {
            unsigned int vv[4];
#pragma unroll
            for (int j = 0; j < 4; j++) vv[j] = sbase[(size_t)EDGE_S(rrA[j]) * 32];
            CONSU8(rrA, vv)
        }
    }
    int t0 = nfull << 2;
    if (t0 < cnt) {
        unsigned int rrt[4], vv[4];
#pragma unroll
        for (int j = 0; j < 4; j++) {
            int t = t0 + j;
            rrt[j] = csr[t < cnt ? k0 + 2 * t : beg];
        }
#pragma unroll
        for (int j = 0; j < 4; j++) vv[j] = sbase[(size_t)EDGE_S(rrt[j]) * 32];
#pragma unroll
        for (int j = 0; j < 4; j++) {
            float we = (t0 + j < cnt) ? EDGE_W(rrt[j]) : 0.f;
            f32x2 lo = __builtin_amdgcn_cvt_pk_f32_fp8(vv[j], false);
            f32x2 hi = __builtin_amdgcn_cvt_pk_f32_fp8(vv[j], true);
            a0 = fmaf(we, lo.x, a0);
            a1 = fmaf(we, lo.y, a1);
            a2 = fmaf(we, hi.x, a2);
            a3 = fmaf(we, hi.y, a3);
        }
    }
#undef CONSU8
    a0 += __shfl_xor(a0, 32, 64);
    a1 += __shfl_xor(a1, 32, 64);
    a2 += __shfl_xor(a2, 32, 64);
    a3 += __shfl_xor(a3, 32, 64);
    if (lane < 32) {
        int m = lane >> 1, sb = 4 * (lane & 1);
        float av[4] = {a0, a1, a2, a3};
#pragma unroll
        for (int j = 0; j < 4; j++) {
            int L = (sb + j) * 16 + m;
            if (L >= 40 && L < 80) T2a[(size_t)i * 40 + (L - 40)] = f2bf(av[j]);
            else if (L >= 80 && L < 120) T8b[(size_t)i * 40 + (L - 80)] = pack_fp8x1(av[j]);
        }
    }
}

// ---------------- fused second-hop prop + log_softmax -----------------------
// 6 groups x 10 lanes, batch-of-4 per group + prefetch + masked final batch

__global__ __launch_bounds__(256) void lsm_prop_k(const unsigned short* __restrict__ Ub,
                                                  const unsigned short* __restrict__ T2a,
                                                  const unsigned char* __restrict__ T8b,
                                                  const int* __restrict__ rowptr,
                                                  const unsigned int* __restrict__ csr,
                                                  const float* __restrict__ dinv,
                                                  const float* __restrict__ b2,
                                                  float* __restrict__ out, int n) {
    int wave = threadIdx.x >> 6;
    int lane = threadIdx.x & 63;
    int i = blockIdx.x * 4 + wave;
    if (i >= n) return;
    int beg = rowptr[i], end = rowptr[i + 1];
    float di = dinv[i];
    int g = lane / 10;           // 0..6 (lanes 60..63 inactive)
    int c = lane - g * 10;       // 0..9
    bool act = lane < 60;
    const unsigned int* sb = (const unsigned int*)T8b + c;  // row stride 10 uints
    float a0 = 0.f, a1 = 0.f, a2 = 0.f, a3 = 0.f;
    if (lane < 10) {  // self term counted once (group 0)
        unsigned int sv = sb[(size_t)i * 10];
        float w = di * di;
        f32x2 lo = __builtin_amdgcn_cvt_pk_f32_fp8(sv, false);
        f32x2 hi = __builtin_amdgcn_cvt_pk_f32_fp8(sv, true);
        a0 = w * lo.x; a1 = w * lo.y; a2 = w * hi.x; a3 = w * hi.y;
    }

#define CONSLS(rr, vv)                                                        \
    _Pragma("unroll") for (int j = 0; j < 4; j++) {                           \
        float we = EDGE_W(rr[j]);                                             \
        f32x2 lo = __builtin_amdgcn_cvt_pk_f32_fp8(vv[j], false);             \
        f32x2 hi = __builtin_amdgcn_cvt_pk_f32_fp8(vv[j], true);              \
        a0 = fmaf(we, lo.x, a0);                                              \
        a1 = fmaf(we, lo.y, a1);                                              \
        a2 = fmaf(we, hi.x, a2);                                              \
        a3 = fmaf(we, hi.y, a3);                                              \
    }

    int k0 = beg + g;
    int cnt = (act && k0 < end) ? ((end - k0 + 5) / 6) : 0;  // edges this group owns
    int nfull = cnt >> 2;
    unsigned int rrA[4], rrB[4];
    if (nfull > 0) {
#pragma unroll
        for (int j = 0; j < 4; j++) rrA[j] = csr[k0 + 6 * j];
        int it = 0;
        while (it + 2 <= nfull) {
            {
                unsigned int vv[4];
#pragma unroll
                for (int j = 0; j < 4; j++) vv[j] = sb[(size_t)EDGE_S(rrA[j]) * 10];
#pragma unroll
                for (int j = 0; j < 4; j++) rrB[j] = csr[k0 + (it + 1) * 24 + 6 * j];
                CONSLS(rrA, vv)
            }
            {
                unsigned int vv[4];
#pragma unroll
                for (int j = 0; j < 4; j++) vv[j] = sb[(size_t)EDGE_S(rrB[j]) * 10];
                if (it + 2 < nfull) {
#pragma unroll
                    for (int j = 0; j < 4; j++) rrA[j] = csr[k0 + (it + 2) * 24 + 6 * j];
                }
                CONSLS(rrB, vv)
            }
            it += 2;
        }
        if (it < nfull) {
            unsigned int vv[4];
#pragma unroll
            for (int j = 0; j < 4; j++) vv[j] = sb[(size_t)EDGE_S(rrA[j]) * 10];
            CONSLS(rrA, vv)
        }
    }
    int t0 = nfull << 2;
    if (t0 < cnt) {
        unsigned int rrt[4], vv[4];
#pragma unroll
        for (int j = 0; j < 4; j++) {
            int t = t0 + j;
            rrt[j] = csr[t < cnt ? k0 + 6 * t : beg];
        }
#pragma unroll
        for (int j = 0; j < 4; j++) vv[j] = sb[(size_t)EDGE_S(rrt[j]) * 10];
#pragma unroll
        for (int j = 0; j < 4; j++) {
            float we = (t0 + j < cnt) ? EDGE_W(rrt[j]) : 0.f;
            f32x2 lo = __builtin_amdgcn_cvt_pk_f32_fp8(vv[j], false);
            f32x2 hi = __builtin_amdgcn_cvt_pk_f32_fp8(vv[j], true);
            a0 = fmaf(we, lo.x, a0);
            a1 = fmaf(we, lo.y, a1);
            a2 = fmaf(we, hi.x, a2);
            a3 = fmaf(we, hi.y, a3);
        }
    }
#undef CONSLS
    // reduce the 6 group partials into lanes 0..9 (results valid there only)
    float r0s = a0, r1s = a1, r2s = a2, r3s = a3;
#pragma unroll
    for (int g2 = 1; g2 < 6; g2++) {
        r0s += __shfl(a0, lane + 10 * g2, 64);
        r1s += __shfl(a1, lane + 10 * g2, 64);
        r2s += __shfl(a2, lane + 10 * g2, 64);
        r3s += __shfl(a3, lane + 10 * g2, 64);
    }
    // redistribute: lane j1=lane+64 needs col idx=j1-80 from lane idx>>2, comp idx&3
    int j1 = lane + 64;
    int idx = j1 - 80;
    int srcl = (idx < 0) ? 0 : (idx >> 2);
    float s0v = __shfl(r0s, srcl, 64);
    float s1v = __shfl(r1s, srcl, 64);
    float s2v = __shfl(r2s, srcl, 64);
    float s3v = __shfl(r3s, srcl, 64);
    int comp = idx & 3;
    float pv = (comp == 0) ? s0v : (comp == 1) ? s1v : (comp == 2) ? s2v : s3v;
    float v0, v1;
    {
        int j = lane;  // 0..63
        float v = (j >= 40) ? bf2f(T2a[(size_t)i * 40 + (j - 40)]) : bf2f(Ub[(size_t)i * L2WP + j]);
        v0 = v + b2[j];
    }
    if (j1 < 120) {
        float v = (j1 < 80) ? bf2f(T2a[(size_t)i * 40 + (j1 - 40)]) : pv;
        v1 = v + b2[j1];
    } else {
        v1 = -INFINITY;
    }
    float m = fmaxf(v0, v1);
    for (int off = 32; off; off >>= 1) m = fmaxf(m, __shfl_xor(m, off, 64));
    float s = expf(v0 - m) + ((j1 < 120) ? expf(v1 - m) : 0.f);
    for (int off = 32; off; off >>= 1) s += __shfl_xor(s, off, 64);
    float ls = logf(s) + m;
    out[(size_t)i * 120 + lane] = v0 - ls;
    if (j1 < 120) out[(size_t)i * 120 + j1] = v1 - ls;
}

// ---------------- launch ----------------

static inline size_t align256(size_t x) { return (x + 255) & ~(size_t)255; }

extern "C" void kernel_launch(void* const* d_in, const int* in_sizes, int n_in,
                              void* d_out, int out_size, void* d_ws, size_t ws_size,
                              hipStream_t stream) {
    const float* x = (const float*)d_in[0];
    const int* ei = (const int*)d_in[1];
    const float* W1_0 = (const float*)d_in[2];
    const float* W1_1 = (const float*)d_in[3];
    const float* W1_2 = (const float*)d_in[4];
    const float* b1 = (const float*)d_in[5];
    const float* W2_0 = (const float*)d_in[6];
    const float* W2_1 = (const float*)d_in[7];
    const float* W2_2 = (const float*)d_in[8];
    const float* b2 = (const float*)d_in[9];
    float* out = (float*)d_out;

    const int n = N_NODES;
    const int E = in_sizes[1] / 2;
    const int nb = (n + 255) / 256;
    const int n2 = NBUK * NBLK1;
    const int nb2 = (n2 + 255) / 256;

    char* p = (char*)d_ws;
    size_t off = 0;
    auto alloc = [&](size_t bytes) {
        void* r = p + off;
        off = align256(off + bytes);
        return r;
    };
    int* cnt = (int*)alloc((size_t)n * 4);
    int* rowptr = (int*)alloc((size_t)(n + 1) * 4);
    int* bsum = (int*)alloc((size_t)nb * 4);
    float* dinv = (float*)alloc((size_t)n * 4);
    unsigned int* csr = (unsigned int*)alloc((size_t)E * 4);
    int* cnt2 = (int*)alloc((size_t)n2 * 4);
    int* off2 = (int*)alloc((size_t)n2 * 4);
    int* bsum2 = (int*)alloc((size_t)nb2 * 4);
    int* tot2 = (int*)alloc(4);
    unsigned int* stage = (unsigned int*)alloc((size_t)E * 4);
    unsigned short* Bp1 = (unsigned short*)alloc((size_t)N1PACK * 2);
    unsigned short* Bp2 = (unsigned short*)alloc((size_t)N2PACK * 2);
    unsigned short* Hb = (unsigned short*)alloc((size_t)n * L1W * 2);
    unsigned char* Y8 = (unsigned char*)alloc((size_t)n * 256);
    unsigned char* T8 = (unsigned char*)alloc((size_t)n * 128);
    unsigned short* Ub = (unsigned short*)alloc((size_t)n * L2WP * 2);
    unsigned char* U8 = (unsigned char*)alloc((size_t)n * 128);
    unsigned short* T2a = (unsigned short*)alloc((size_t)n * C_OUT * 2);
    unsigned char* T8b = (unsigned char*)alloc((size_t)n * C_OUT);
    (void)ws_size;

    // 1. fused: per-node degree + bucket hist + weight pack (one pass)
    hipMemsetAsync(cnt, 0, (size_t)n * 4, stream);
    fhist_k<<<NBLK1 + PACKB, 256, 0, stream>>>(ei, W1_0, W1_1, W1_2, W2_0, W2_1, W2_2,
                                               cnt, cnt2, Bp1, Bp2, E);

    // 2. fused scans (node chain: rowptr+dinv; bucket chain: off2)
    fscan1_k<<<nb + nb2, 256, 0, stream>>>(cnt, bsum, n, cnt2, bsum2, n2, nb);
    fscan2_k<<<2, 256, 0, stream>>>(bsum, rowptr + n, nb, bsum2, tot2, nb2);
    fscan3_k<<<nb + nb2, 256, 0, stream>>>(cnt, bsum, rowptr, dinv, n,
                                           cnt2, bsum2, off2, n2, nb);

    // 3. two-phase binned scatter -> csr
    stage_k<<<NBLK1, 256, 0, stream>>>(ei, off2, stage, E);
    scatter2_k<<<NBUK, 256, 0, stream>>>(stage, off2, rowptr, dinv, csr, E, n);

    // 4. layer 1 GEMM (z1 -> Hb bf16, y2 -> Y8 fp8 transposed)
    mgemm1_k<<<(n + 63) / 64, 256, 0, stream>>>(x, Bp1, b1, Hb, Y8, n);
    prop256f_k<<<(n + 3) / 4, 256, 0, stream>>>(Y8, Hb, T8, rowptr, csr, dinv, b1, n);
    prop128f_k<<<(n + 3) / 4, 256, 0, stream>>>(T8, Hb, rowptr, csr, dinv, b1, n);

    // 5. layer 2 GEMM -> Ub bf16 (cols<48) + U8 fp8 (1 line/row)
    mgemm2_k<<<(n + 63) / 64, 256, 0, stream>>>(Hb, Bp2, Ub, U8, n);
    propU8_k<<<(n + 3) / 4, 256, 0, stream>>>(U8, T2a, T8b, rowptr, csr, dinv, n);

    // 6. fused second hop + log_softmax
    lsm_prop_k<<<(n + 3) / 4, 256, 0, stream>>>(Ub, T2a, T8b, rowptr, csr, dinv, b2, out, n);
}